// Round 2
// baseline (3951.506 us; speedup 1.0000x reference)
//
#include <hip/hip_runtime.h>

#define BB 4
#define HH 64
#define WW 64
#define CC 96
#define DIN 192
#define NS 4
#define RR 6
#define KK 4
#define LL 4096               // HH*WW
#define NPOS (BB*LL)          // 16384 positions per modality
#define NPD ((size_t)NPOS*DIN)
#define NDBC ((size_t)BB*KK*LL*14)

// canonical spatial position for scan-direction k at scan step l
__device__ __forceinline__ int map_pos(int k, int l){
  switch(k){
    case 0: return l;
    case 1: { int wi=l>>6, hi=l&63; return hi*WW+wi; }     // (w,h) flatten -> h*W+w
    case 2: return LL-1-l;
    default:{ int lr=LL-1-l; int wi=lr>>6, hi=lr&63; return hi*WW+wi; }
  }
}

// ---------------- K1: in_proj (bhwc,dc->bhwd) for both modalities ----------
__global__ __launch_bounds__(DIN) void inproj_kernel(
    const float* __restrict__ x_rgb, const float* __restrict__ x_e,
    const float* __restrict__ w_r,   const float* __restrict__ w_e,
    float* __restrict__ xproj_r,    float* __restrict__ xproj_e){
  int blk = blockIdx.x;                 // m*NPOS + b*LL + p
  int m = blk / NPOS; int rem = blk % NPOS;
  const float* x = m ? x_e : x_rgb;
  const float* w = m ? w_e : w_r;
  float* o = m ? xproj_e : xproj_r;
  __shared__ float xs[CC];
  int t = threadIdx.x;
  if(t < CC) xs[t] = x[(size_t)rem*CC + t];
  __syncthreads();
  const float* wr = w + (size_t)t*CC;
  float acc = 0.f;
  #pragma unroll 8
  for(int c=0;c<CC;c++) acc += xs[c]*wr[c];
  o[(size_t)rem*DIN + t] = acc;
}

// ---------------- K2: depthwise 3x3 conv (SAME, zero pad) + bias + SiLU ----
__global__ __launch_bounds__(DIN) void conv_kernel(
    const float* __restrict__ xproj_r, const float* __restrict__ xproj_e,
    const float* __restrict__ cw_r, const float* __restrict__ cb_r,
    const float* __restrict__ cw_e, const float* __restrict__ cb_e,
    float* __restrict__ xconv_r, float* __restrict__ xconv_e){
  int blk = blockIdx.x;
  int m = blk / NPOS; int rem = blk % NPOS;
  int b = rem / LL, p = rem % LL;
  int y = p >> 6, x = p & 63;           // p = y*WW + x
  const float* in = (m ? xproj_e : xproj_r) + (size_t)b*LL*DIN;
  const float* cw = m ? cw_e : cw_r;
  const float* cb = m ? cb_e : cb_r;
  float* out = m ? xconv_e : xconv_r;
  int d = threadIdx.x;
  float acc = cb[d];
  #pragma unroll
  for(int dy=-1;dy<=1;dy++){
    int yy = y+dy; if(yy<0 || yy>=HH) continue;
    #pragma unroll
    for(int dx=-1;dx<=1;dx++){
      int xx = x+dx; if(xx<0 || xx>=WW) continue;
      acc += in[(size_t)(yy*WW+xx)*DIN + d] * cw[d*9 + (dy+1)*3 + (dx+1)];
    }
  }
  float s = acc / (1.f + __expf(-acc));  // silu
  out[(size_t)(b*LL+p)*DIN + d] = s;
}

// ---------------- K3: x_proj -> (dt_rank 6 | B 4 | C 4) per (m,b,k,l) ------
__global__ __launch_bounds__(256) void projbc_kernel(
    const float* __restrict__ xconv_r, const float* __restrict__ xconv_e,
    const float* __restrict__ xpw,
    float* __restrict__ dtBC_r, float* __restrict__ dtBC_e){
  unsigned id = blockIdx.x*256u + threadIdx.x;
  const unsigned TOT = 2u*BB*KK*LL*14u;
  if(id >= TOT) return;
  int c = id % 14; unsigned r1 = id/14;
  int l = r1 % LL; unsigned r2 = r1/LL;
  int k = r2 % KK; unsigned r3 = r2/KK;
  int b = r3 % BB; int m = r3/BB;
  const float* xc = (m ? xconv_e : xconv_r) + ((size_t)b*LL + map_pos(k,l))*DIN;
  const float* w = xpw + ((size_t)k*14 + c)*DIN;
  float acc = 0.f;
  #pragma unroll 8
  for(int d=0; d<DIN; d++) acc += xc[d]*w[d];
  float* o = m ? dtBC_e : dtBC_r;
  o[(((size_t)b*KK + k)*LL + l)*14 + c] = acc;
}

// ---------------- K4: selective scan, one block per (m,b,k) chain ----------
#define CH 32
__global__ __launch_bounds__(DIN) void scan_kernel(
    const float* __restrict__ xconv_r, const float* __restrict__ xconv_e,
    const float* __restrict__ dtBC_r, const float* __restrict__ dtBC_e,
    const float* __restrict__ dtw, const float* __restrict__ dtb,
    const float* __restrict__ A_logs, const float* __restrict__ Ds,
    float* __restrict__ ym_r, float* __restrict__ ym_e){
  int blk = blockIdx.x;                 // m*16 + b*4 + k
  int m = blk >> 4, b = (blk>>2)&3, k = blk&3;
  int d = threadIdx.x;

  float A[NS], Wd[RR];
  #pragma unroll
  for(int n=0;n<NS;n++) A[n] = -__expf(A_logs[(size_t)(k*DIN+d)*NS + n]);
  #pragma unroll
  for(int r=0;r<RR;r++) Wd[r] = dtw[((size_t)k*DIN + d)*RR + r];
  float bias = dtb[k*DIN+d];
  float Dv = Ds[k*DIN+d];

  const float* xc    = (m ? xconv_e : xconv_r) + (size_t)b*LL*DIN;
  const float* dbc_m = (m ? dtBC_e : dtBC_r) + ((size_t)b*KK + k)*LL*14;  // dt,B: own modality
  const float* dbc_o = (m ? dtBC_r : dtBC_e) + ((size_t)b*KK + k)*LL*14;  // C: other modality
  float* ym = (m ? ym_e : ym_r) + (size_t)b*LL*DIN;

  __shared__ float u_s[CH][DIN];
  __shared__ float db_s[CH][14];
  __shared__ float c_s[CH][NS];

  float h0=0.f,h1=0.f,h2=0.f,h3=0.f;

  for(int l0=0; l0<LL; l0+=CH){
    __syncthreads();
    for(int idx=threadIdx.x; idx<CH*DIN; idx+=DIN){
      int i = idx/DIN, dd = idx%DIN;
      u_s[i][dd] = xc[(size_t)map_pos(k, l0+i)*DIN + dd];
    }
    for(int idx=threadIdx.x; idx<CH*14; idx+=DIN){
      db_s[idx/14][idx%14] = dbc_m[(size_t)l0*14 + idx];
    }
    for(int idx=threadIdx.x; idx<CH*NS; idx+=DIN){
      int i = idx>>2, j = idx&3;
      c_s[i][j] = dbc_o[(size_t)(l0+i)*14 + 10 + j];
    }
    __syncthreads();
    for(int i=0;i<CH;i++){
      float dtr = bias;
      #pragma unroll
      for(int r=0;r<RR;r++) dtr += db_s[i][r]*Wd[r];
      // softplus, stable
      float dt = fmaxf(dtr,0.f) + log1pf(__expf(-fabsf(dtr)));
      float u = u_s[i][d];
      float dtu = dt*u;
      float B0=db_s[i][6], B1=db_s[i][7], B2=db_s[i][8], B3=db_s[i][9];
      h0 = h0*__expf(dt*A[0]) + dtu*B0;
      h1 = h1*__expf(dt*A[1]) + dtu*B1;
      h2 = h2*__expf(dt*A[2]) + dtu*B2;
      h3 = h3*__expf(dt*A[3]) + dtu*B3;
      float y = h0*c_s[i][0] + h1*c_s[i][1] + h2*c_s[i][2] + h3*c_s[i][3];
      y += Dv*u;
      atomicAdd(&ym[(size_t)map_pos(k, l0+i)*DIN + d], y);
    }
  }
}

// ---------------- K5: LayerNorm(192) + out_proj(192->96) + residual --------
__global__ __launch_bounds__(DIN) void ln_out_kernel(
    const float* __restrict__ ym_r, const float* __restrict__ ym_e,
    const float* __restrict__ ln_rg, const float* __restrict__ ln_rb,
    const float* __restrict__ ln_eg, const float* __restrict__ ln_eb,
    const float* __restrict__ opw_r, const float* __restrict__ opw_e,
    const float* __restrict__ x_rgb, const float* __restrict__ x_e,
    float* __restrict__ out){
  int blk = blockIdx.x;                 // m*NPOS + b*LL + p
  int m = blk / NPOS; int rem = blk % NPOS;
  const float* ym = (m ? ym_e : ym_r) + (size_t)rem*DIN;
  int t = threadIdx.x;
  float v = ym[t];
  float s = v, q = v*v;
  #pragma unroll
  for(int off=32; off>0; off>>=1){ s += __shfl_down(s,off); q += __shfl_down(q,off); }
  __shared__ float red[2][3];
  int wid = t>>6;
  if((t&63)==0){ red[0][wid]=s; red[1][wid]=q; }
  __syncthreads();
  float S = red[0][0]+red[0][1]+red[0][2];
  float Q = red[1][0]+red[1][1]+red[1][2];
  float mu  = S*(1.f/DIN);
  float var = Q*(1.f/DIN) - mu*mu;
  float inv = rsqrtf(var + 1e-5f);
  const float* g  = m ? ln_eg : ln_rg;
  const float* be = m ? ln_eb : ln_rb;
  __shared__ float yn[DIN];
  yn[t] = (v-mu)*inv*g[t] + be[t];
  __syncthreads();
  if(t < CC){
    const float* w = (m ? opw_e : opw_r) + (size_t)t*DIN;
    float acc = 0.f;
    #pragma unroll 8
    for(int dd=0; dd<DIN; dd++) acc += yn[dd]*w[dd];
    const float* xin = m ? x_e : x_rgb;
    size_t oi = (size_t)m*NPOS*CC + (size_t)rem*CC + t;
    out[oi] = acc + xin[(size_t)rem*CC + t];
  }
}

extern "C" void kernel_launch(void* const* d_in, const int* in_sizes, int n_in,
                              void* d_out, int out_size, void* d_ws, size_t ws_size,
                              hipStream_t stream){
  const float* x_rgb = (const float*)d_in[0];
  const float* x_e   = (const float*)d_in[1];
  const float* ipw_r = (const float*)d_in[2];
  const float* ipw_e = (const float*)d_in[3];
  const float* cw_r  = (const float*)d_in[4];
  const float* cb_r  = (const float*)d_in[5];
  const float* cw_e  = (const float*)d_in[6];
  const float* cb_e  = (const float*)d_in[7];
  const float* xpw   = (const float*)d_in[8];
  const float* dtw   = (const float*)d_in[9];
  const float* dtb   = (const float*)d_in[10];
  const float* Alog  = (const float*)d_in[11];
  const float* Ds_   = (const float*)d_in[12];
  const float* ln_rg = (const float*)d_in[13];
  const float* ln_rb = (const float*)d_in[14];
  const float* ln_eg = (const float*)d_in[15];
  const float* ln_eb = (const float*)d_in[16];
  const float* opw_r = (const float*)d_in[17];
  const float* opw_e = (const float*)d_in[18];
  float* out = (float*)d_out;

  float* ws = (float*)d_ws;
  // layout: [xproj_r|xproj_e (reused as ym_r|ym_e)][xconv_r][xconv_e][dtBC_r][dtBC_e]
  float* xproj_r = ws;
  float* xproj_e = ws + NPD;
  float* xconv_r = ws + 2*NPD;
  float* xconv_e = ws + 3*NPD;
  float* dtBC_r  = ws + 4*NPD;
  float* dtBC_e  = ws + 4*NPD + NDBC;
  float* ym_r = xproj_r;   // xproj dead after conv
  float* ym_e = xproj_e;

  inproj_kernel<<<2*NPOS, DIN, 0, stream>>>(x_rgb, x_e, ipw_r, ipw_e, xproj_r, xproj_e);
  conv_kernel<<<2*NPOS, DIN, 0, stream>>>(xproj_r, xproj_e, cw_r, cb_r, cw_e, cb_e, xconv_r, xconv_e);
  hipMemsetAsync(ym_r, 0, 2*NPD*sizeof(float), stream);  // zero merge accumulators (stream-ordered after conv)
  {
    unsigned tot = 2u*BB*KK*LL*14u;
    projbc_kernel<<<(tot+255)/256, 256, 0, stream>>>(xconv_r, xconv_e, xpw, dtBC_r, dtBC_e);
  }
  scan_kernel<<<2*BB*KK, DIN, 0, stream>>>(xconv_r, xconv_e, dtBC_r, dtBC_e,
                                           dtw, dtb, Alog, Ds_, ym_r, ym_e);
  ln_out_kernel<<<2*NPOS, DIN, 0, stream>>>(ym_r, ym_e, ln_rg, ln_rb, ln_eg, ln_eb,
                                            opw_r, opw_e, x_rgb, x_e, out);
}

// Round 4
// 704.966 us; speedup vs baseline: 5.6052x; 5.6052x over previous
//
#include <hip/hip_runtime.h>

#define BB 4
#define HH 64
#define WW 64
#define CC 96
#define DIN 192
#define NS 4
#define RR 6
#define KK 4
#define LL 4096               // HH*WW
#define NPOS (BB*LL)          // 16384 positions per modality
#define NPD ((size_t)NPOS*DIN)
#define NDBC ((size_t)BB*KK*LL*14)
#define NCHUNK 64
#define CLEN 64               // NCHUNK*CLEN == LL
#define NCHAIN 32             // 2 mods * 4 b * 4 k
#define PB 8                  // positions per block in inproj/ln_out

// canonical spatial position for scan-direction k at scan step l
__device__ __forceinline__ int map_pos(int k, int l){
  switch(k){
    case 0: return l;
    case 1: { int wi=l>>6, hi=l&63; return hi*WW+wi; }     // (w,h) flatten -> h*W+w
    case 2: return LL-1-l;
    default:{ int lr=LL-1-l; int wi=lr>>6, hi=lr&63; return hi*WW+wi; }
  }
}

// ---------------- K1: in_proj (bhwc,dc->bhwd), 8 positions per block -------
__global__ __launch_bounds__(DIN) void inproj_kernel(
    const float* __restrict__ x_rgb, const float* __restrict__ x_e,
    const float* __restrict__ w_r,   const float* __restrict__ w_e,
    float* __restrict__ xproj_r,    float* __restrict__ xproj_e){
  int blk = blockIdx.x;                 // m*(NPOS/PB) + g
  int m = blk / (NPOS/PB); int g = blk % (NPOS/PB);
  size_t rem0 = (size_t)g * PB;
  const float* x = m ? x_e : x_rgb;
  const float* w = m ? w_e : w_r;
  float* o = m ? xproj_e : xproj_r;
  __shared__ float xs[PB][CC];
  __shared__ float wt[DIN][17];         // 16 cols + pad
  int t = threadIdx.x;
  for(int idx=t; idx<PB*CC; idx+=DIN) xs[idx/CC][idx%CC] = x[rem0*CC + idx];
  float acc[PB];
  #pragma unroll
  for(int p=0;p<PB;p++) acc[p]=0.f;
  for(int c0=0; c0<CC; c0+=16){
    __syncthreads();
    for(int idx=t; idx<DIN*16; idx+=DIN){
      int dd = idx>>4, cc = idx&15;
      wt[dd][cc] = w[(size_t)dd*CC + c0 + cc];
    }
    __syncthreads();
    #pragma unroll
    for(int cc=0; cc<16; cc++){
      float wv = wt[t][cc];
      #pragma unroll
      for(int p=0;p<PB;p++) acc[p] += xs[p][c0+cc]*wv;
    }
  }
  #pragma unroll
  for(int p=0;p<PB;p++) o[(rem0+p)*DIN + t] = acc[p];
}

// ---------------- K2: depthwise 3x3 conv (SAME, zero pad) + bias + SiLU ----
__global__ __launch_bounds__(DIN) void conv_kernel(
    const float* __restrict__ xproj_r, const float* __restrict__ xproj_e,
    const float* __restrict__ cw_r, const float* __restrict__ cb_r,
    const float* __restrict__ cw_e, const float* __restrict__ cb_e,
    float* __restrict__ xconv_r, float* __restrict__ xconv_e){
  int blk = blockIdx.x;
  int m = blk / NPOS; int rem = blk % NPOS;
  int b = rem / LL, p = rem % LL;
  int y = p >> 6, x = p & 63;           // p = y*WW + x
  const float* in = (m ? xproj_e : xproj_r) + (size_t)b*LL*DIN;
  const float* cw = m ? cw_e : cw_r;
  const float* cb = m ? cb_e : cb_r;
  float* out = m ? xconv_e : xconv_r;
  int d = threadIdx.x;
  float acc = cb[d];
  #pragma unroll
  for(int dy=-1;dy<=1;dy++){
    int yy = y+dy; if(yy<0 || yy>=HH) continue;
    #pragma unroll
    for(int dx=-1;dx<=1;dx++){
      int xx = x+dx; if(xx<0 || xx>=WW) continue;
      acc += in[(size_t)(yy*WW+xx)*DIN + d] * cw[d*9 + (dy+1)*3 + (dx+1)];
    }
  }
  float s = acc / (1.f + __expf(-acc));  // silu
  out[(size_t)(b*LL+p)*DIN + d] = s;
}

// ---------------- K3: x_proj -> (dt_rank 6 | B 4 | C 4) per (m,b,k,l) ------
__global__ __launch_bounds__(256) void projbc_kernel(
    const float* __restrict__ xconv_r, const float* __restrict__ xconv_e,
    const float* __restrict__ xpw,
    float* __restrict__ dtBC_r, float* __restrict__ dtBC_e){
  unsigned id = blockIdx.x*256u + threadIdx.x;
  const unsigned TOT = 2u*BB*KK*LL*14u;
  if(id >= TOT) return;
  int c = id % 14; unsigned r1 = id/14;
  int l = r1 % LL; unsigned r2 = r1/LL;
  int k = r2 % KK; unsigned r3 = r2/KK;
  int b = r3 % BB; int m = r3/BB;
  const float* xc = (m ? xconv_e : xconv_r) + ((size_t)b*LL + map_pos(k,l))*DIN;
  const float* w = xpw + ((size_t)k*14 + c)*DIN;
  float acc = 0.f;
  #pragma unroll 8
  for(int d=0; d<DIN; d++) acc += xc[d]*w[d];
  float* o = m ? dtBC_e : dtBC_r;
  o[(((size_t)b*KK + k)*LL + l)*14 + c] = acc;
}

// ------- K4a: per-chunk local scan -> (end state S, sum of dt) -------------
__global__ __launch_bounds__(DIN) void scan_p1_kernel(
    const float* __restrict__ xconv_r, const float* __restrict__ xconv_e,
    const float* __restrict__ dtBC_r, const float* __restrict__ dtBC_e,
    const float* __restrict__ dtw, const float* __restrict__ dtb,
    const float* __restrict__ A_logs,
    float* __restrict__ trans_S, float* __restrict__ sumdt){
  int ch = blockIdx.x / NCHUNK;         // m*16 + b*4 + k
  int cidx = blockIdx.x % NCHUNK;
  int m = ch >> 4, b = (ch>>2)&3, k = ch&3;
  int d = threadIdx.x;
  int l0 = cidx*CLEN;

  float A[NS], Wd[RR];
  #pragma unroll
  for(int n=0;n<NS;n++) A[n] = -__expf(A_logs[(size_t)(k*DIN+d)*NS + n]);
  #pragma unroll
  for(int r=0;r<RR;r++) Wd[r] = dtw[((size_t)k*DIN + d)*RR + r];
  float bias = dtb[k*DIN+d];

  const float* xc    = (m ? xconv_e : xconv_r) + (size_t)b*LL*DIN;
  const float* dbc_m = (m ? dtBC_e : dtBC_r) + ((size_t)b*KK + k)*LL*14;

  __shared__ float db_s[CLEN][14];
  for(int idx=threadIdx.x; idx<CLEN*14; idx+=DIN)
    db_s[idx/14][idx%14] = dbc_m[(size_t)l0*14 + idx];
  __syncthreads();

  float h0=0.f,h1=0.f,h2=0.f,h3=0.f,sd=0.f;
  for(int i=0;i<CLEN;i++){
    float dtr = bias;
    #pragma unroll
    for(int r=0;r<RR;r++) dtr += db_s[i][r]*Wd[r];
    float dt = fmaxf(dtr,0.f) + log1pf(__expf(-fabsf(dtr)));
    sd += dt;
    float u = xc[(size_t)map_pos(k, l0+i)*DIN + d];
    float dtu = dt*u;
    h0 = h0*__expf(dt*A[0]) + dtu*db_s[i][6];
    h1 = h1*__expf(dt*A[1]) + dtu*db_s[i][7];
    h2 = h2*__expf(dt*A[2]) + dtu*db_s[i][8];
    h3 = h3*__expf(dt*A[3]) + dtu*db_s[i][9];
  }
  size_t base = ((size_t)(ch*NCHUNK + cidx)*NS)*DIN + d;
  trans_S[base          ] = h0;
  trans_S[base +   DIN  ] = h1;
  trans_S[base + 2*DIN  ] = h2;
  trans_S[base + 3*DIN  ] = h3;
  sumdt[(size_t)(ch*NCHUNK + cidx)*DIN + d] = sd;
}

// ------- K4b: sequential inter-chunk scan -> entering state per chunk ------
__global__ __launch_bounds__(DIN) void scan_p2_kernel(
    const float* __restrict__ trans_S, const float* __restrict__ sumdt,
    const float* __restrict__ A_logs, float* __restrict__ hin){
  int ch = blockIdx.x; int k = ch & 3; int d = threadIdx.x;
  float A[NS];
  #pragma unroll
  for(int n=0;n<NS;n++) A[n] = -__expf(A_logs[(size_t)(k*DIN+d)*NS + n]);
  float h[NS] = {0.f,0.f,0.f,0.f};
  for(int c=0;c<NCHUNK;c++){
    size_t base = ((size_t)(ch*NCHUNK + c)*NS)*DIN + d;
    #pragma unroll
    for(int n=0;n<NS;n++) hin[base + (size_t)n*DIN] = h[n];
    float sd = sumdt[(size_t)(ch*NCHUNK + c)*DIN + d];
    #pragma unroll
    for(int n=0;n<NS;n++) h[n] = h[n]*__expf(A[n]*sd) + trans_S[base + (size_t)n*DIN];
  }
}

// ------- K4c: per-chunk scan with true entering state -> y (merged) --------
__global__ __launch_bounds__(DIN) void scan_p3_kernel(
    const float* __restrict__ xconv_r, const float* __restrict__ xconv_e,
    const float* __restrict__ dtBC_r, const float* __restrict__ dtBC_e,
    const float* __restrict__ dtw, const float* __restrict__ dtb,
    const float* __restrict__ A_logs, const float* __restrict__ Ds,
    const float* __restrict__ hin,
    float* __restrict__ ym_r, float* __restrict__ ym_e){
  int ch = blockIdx.x / NCHUNK;
  int cidx = blockIdx.x % NCHUNK;
  int m = ch >> 4, b = (ch>>2)&3, k = ch&3;
  int d = threadIdx.x;
  int l0 = cidx*CLEN;

  float A[NS], Wd[RR];
  #pragma unroll
  for(int n=0;n<NS;n++) A[n] = -__expf(A_logs[(size_t)(k*DIN+d)*NS + n]);
  #pragma unroll
  for(int r=0;r<RR;r++) Wd[r] = dtw[((size_t)k*DIN + d)*RR + r];
  float bias = dtb[k*DIN+d];
  float Dv = Ds[k*DIN+d];

  const float* xc    = (m ? xconv_e : xconv_r) + (size_t)b*LL*DIN;
  const float* dbc_m = (m ? dtBC_e : dtBC_r) + ((size_t)b*KK + k)*LL*14;  // dt,B: own modality
  const float* dbc_o = (m ? dtBC_r : dtBC_e) + ((size_t)b*KK + k)*LL*14;  // C: other modality
  float* ym = (m ? ym_e : ym_r) + (size_t)b*LL*DIN;

  __shared__ float db_s[CLEN][14];
  __shared__ float c_s[CLEN][NS];
  for(int idx=threadIdx.x; idx<CLEN*14; idx+=DIN)
    db_s[idx/14][idx%14] = dbc_m[(size_t)l0*14 + idx];
  for(int idx=threadIdx.x; idx<CLEN*NS; idx+=DIN){
    int i = idx>>2, j = idx&3;
    c_s[i][j] = dbc_o[(size_t)(l0+i)*14 + 10 + j];
  }
  __syncthreads();

  size_t hbase = ((size_t)(ch*NCHUNK + cidx)*NS)*DIN + d;
  float h0=hin[hbase], h1=hin[hbase+DIN], h2=hin[hbase+2*DIN], h3=hin[hbase+3*DIN];

  for(int i=0;i<CLEN;i++){
    float dtr = bias;
    #pragma unroll
    for(int r=0;r<RR;r++) dtr += db_s[i][r]*Wd[r];
    float dt = fmaxf(dtr,0.f) + log1pf(__expf(-fabsf(dtr)));
    int pos = map_pos(k, l0+i);
    float u = xc[(size_t)pos*DIN + d];
    float dtu = dt*u;
    h0 = h0*__expf(dt*A[0]) + dtu*db_s[i][6];
    h1 = h1*__expf(dt*A[1]) + dtu*db_s[i][7];
    h2 = h2*__expf(dt*A[2]) + dtu*db_s[i][8];
    h3 = h3*__expf(dt*A[3]) + dtu*db_s[i][9];
    float y = h0*c_s[i][0] + h1*c_s[i][1] + h2*c_s[i][2] + h3*c_s[i][3] + Dv*u;
    atomicAdd(&ym[(size_t)pos*DIN + d], y);
  }
}

// ---------------- K5: LayerNorm(192) + out_proj(192->96) + residual --------
__global__ __launch_bounds__(DIN) void ln_out_kernel(
    const float* __restrict__ ym_r, const float* __restrict__ ym_e,
    const float* __restrict__ ln_rg, const float* __restrict__ ln_rb,
    const float* __restrict__ ln_eg, const float* __restrict__ ln_eb,
    const float* __restrict__ opw_r, const float* __restrict__ opw_e,
    const float* __restrict__ x_rgb, const float* __restrict__ x_e,
    float* __restrict__ out){
  int blk = blockIdx.x;                 // m*(NPOS/PB) + g
  int m = blk / (NPOS/PB); int g = blk % (NPOS/PB);
  size_t rem0 = (size_t)g * PB;
  const float* ym = (m ? ym_e : ym_r) + rem0*DIN;
  int t = threadIdx.x;
  int wid = t>>6;

  float v[PB];
  #pragma unroll
  for(int p=0;p<PB;p++) v[p] = ym[(size_t)p*DIN + t];

  __shared__ float red_s[PB][3], red_q[PB][3];
  #pragma unroll
  for(int p=0;p<PB;p++){
    float s = v[p], q = v[p]*v[p];
    #pragma unroll
    for(int off=32; off>0; off>>=1){ s += __shfl_down(s,off); q += __shfl_down(q,off); }
    if((t&63)==0){ red_s[p][wid]=s; red_q[p][wid]=q; }
  }
  __syncthreads();

  const float* gg = m ? ln_eg : ln_rg;
  const float* be = m ? ln_eb : ln_rb;
  __shared__ float yn_s[PB][DIN];
  float gv = gg[t], bv = be[t];
  #pragma unroll
  for(int p=0;p<PB;p++){
    float S = red_s[p][0]+red_s[p][1]+red_s[p][2];
    float Q = red_q[p][0]+red_q[p][1]+red_q[p][2];
    float mu  = S*(1.f/DIN);
    float var = Q*(1.f/DIN) - mu*mu;
    float inv = rsqrtf(var + 1e-5f);
    yn_s[p][t] = (v[p]-mu)*inv*gv + bv;
  }
  __syncthreads();

  // out-proj: thread t -> c = t%96, positions {t/96, t/96+2, t/96+4, t/96+6}
  int c = t % CC;
  int pbase = t / CC;                    // 0 or 1
  const float* w = (m ? opw_e : opw_r) + (size_t)c*DIN;
  float acc[4] = {0.f,0.f,0.f,0.f};
  for(int dd=0; dd<DIN; dd++){
    float wv = w[dd];
    #pragma unroll
    for(int pp=0;pp<4;pp++) acc[pp] += yn_s[pbase + 2*pp][dd]*wv;
  }
  const float* xin = m ? x_e : x_rgb;
  #pragma unroll
  for(int pp=0;pp<4;pp++){
    size_t rem = rem0 + pbase + 2*pp;
    size_t oi = (size_t)m*NPOS*CC + rem*CC + c;
    out[oi] = acc[pp] + xin[rem*CC + c];
  }
}

extern "C" void kernel_launch(void* const* d_in, const int* in_sizes, int n_in,
                              void* d_out, int out_size, void* d_ws, size_t ws_size,
                              hipStream_t stream){
  const float* x_rgb = (const float*)d_in[0];
  const float* x_e   = (const float*)d_in[1];
  const float* ipw_r = (const float*)d_in[2];
  const float* ipw_e = (const float*)d_in[3];
  const float* cw_r  = (const float*)d_in[4];
  const float* cb_r  = (const float*)d_in[5];
  const float* cw_e  = (const float*)d_in[6];
  const float* cb_e  = (const float*)d_in[7];
  const float* xpw   = (const float*)d_in[8];
  const float* dtw   = (const float*)d_in[9];
  const float* dtb   = (const float*)d_in[10];
  const float* Alog  = (const float*)d_in[11];
  const float* Ds_   = (const float*)d_in[12];
  const float* ln_rg = (const float*)d_in[13];
  const float* ln_rb = (const float*)d_in[14];
  const float* ln_eg = (const float*)d_in[15];
  const float* ln_eb = (const float*)d_in[16];
  const float* opw_r = (const float*)d_in[17];
  const float* opw_e = (const float*)d_in[18];
  float* out = (float*)d_out;

  float* ws = (float*)d_ws;
  float* xproj_r = ws;
  float* xproj_e = ws + NPD;
  float* xconv_r = ws + 2*NPD;
  float* xconv_e = ws + 3*NPD;
  float* dtBC_r  = ws + 4*NPD;
  float* dtBC_e  = ws + 4*NPD + NDBC;
  float* trans_S = ws + 4*NPD + 2*NDBC;                         // NCHAIN*NCHUNK*NS*DIN
  float* sumdt   = trans_S + (size_t)NCHAIN*NCHUNK*NS*DIN;      // NCHAIN*NCHUNK*DIN
  float* hin     = sumdt   + (size_t)NCHAIN*NCHUNK*DIN;         // NCHAIN*NCHUNK*NS*DIN
  float* ym_r = xproj_r;   // xproj dead after conv
  float* ym_e = xproj_e;

  inproj_kernel<<<2*NPOS/PB, DIN, 0, stream>>>(x_rgb, x_e, ipw_r, ipw_e, xproj_r, xproj_e);
  conv_kernel<<<2*NPOS, DIN, 0, stream>>>(xproj_r, xproj_e, cw_r, cb_r, cw_e, cb_e, xconv_r, xconv_e);
  {
    unsigned tot = 2u*BB*KK*LL*14u;
    projbc_kernel<<<(tot+255)/256, 256, 0, stream>>>(xconv_r, xconv_e, xpw, dtBC_r, dtBC_e);
  }
  scan_p1_kernel<<<NCHAIN*NCHUNK, DIN, 0, stream>>>(xconv_r, xconv_e, dtBC_r, dtBC_e,
                                                    dtw, dtb, Alog, trans_S, sumdt);
  scan_p2_kernel<<<NCHAIN, DIN, 0, stream>>>(trans_S, sumdt, Alog, hin);
  hipMemsetAsync(ym_r, 0, 2*NPD*sizeof(float), stream);  // zero merge accumulators (after conv: xproj dead)
  scan_p3_kernel<<<NCHAIN*NCHUNK, DIN, 0, stream>>>(xconv_r, xconv_e, dtBC_r, dtBC_e,
                                                    dtw, dtb, Alog, Ds_, hin, ym_r, ym_e);
  ln_out_kernel<<<2*NPOS/PB, DIN, 0, stream>>>(ym_r, ym_e, ln_rg, ln_rb, ln_eg, ln_eb,
                                               opw_r, opw_e, x_rgb, x_e, out);
}

// Round 7
// 544.154 us; speedup vs baseline: 7.2617x; 1.2955x over previous
//
#include <hip/hip_runtime.h>

#define BB 4
#define HH 64
#define WW 64
#define CC 96
#define DIN 192
#define NS 4
#define RR 6
#define KK 4
#define LL 4096               // HH*WW
#define NPOS (BB*LL)          // 16384 positions per modality
#define NPD ((size_t)NPOS*DIN)
#define NDBC ((size_t)BB*KK*LL*14)
#define NCHUNK 64
#define CLEN 64               // NCHUNK*CLEN == LL
#define NCHAIN 32             // 2 mods * 4 b * 4 k
#define PB 8                  // positions per block in inproj/ln_out

// canonical spatial position for scan-direction k at scan step l
__device__ __forceinline__ int map_pos(int k, int l){
  switch(k){
    case 0: return l;
    case 1: { int wi=l>>6, hi=l&63; return hi*WW+wi; }     // (w,h) flatten -> h*W+w
    case 2: return LL-1-l;
    default:{ int lr=LL-1-l; int wi=lr>>6, hi=lr&63; return hi*WW+wi; }
  }
}

// ---------------- K1: in_proj (bhwc,dc->bhwd), 8 positions per block -------
__global__ __launch_bounds__(DIN) void inproj_kernel(
    const float* __restrict__ x_rgb, const float* __restrict__ x_e,
    const float* __restrict__ w_r,   const float* __restrict__ w_e,
    float* __restrict__ xproj_r,    float* __restrict__ xproj_e){
  int blk = blockIdx.x;                 // m*(NPOS/PB) + g
  int m = blk / (NPOS/PB); int g = blk % (NPOS/PB);
  size_t rem0 = (size_t)g * PB;
  const float* x = m ? x_e : x_rgb;
  const float* w = m ? w_e : w_r;
  float* o = m ? xproj_e : xproj_r;
  __shared__ float xs[PB][CC];
  __shared__ float wt[DIN][17];         // 16 cols + pad
  int t = threadIdx.x;
  for(int idx=t; idx<PB*CC; idx+=DIN) xs[idx/CC][idx%CC] = x[rem0*CC + idx];
  float acc[PB];
  #pragma unroll
  for(int p=0;p<PB;p++) acc[p]=0.f;
  for(int c0=0; c0<CC; c0+=16){
    __syncthreads();
    for(int idx=t; idx<DIN*16; idx+=DIN){
      int dd = idx>>4, cc = idx&15;
      wt[dd][cc] = w[(size_t)dd*CC + c0 + cc];
    }
    __syncthreads();
    #pragma unroll
    for(int cc=0; cc<16; cc++){
      float wv = wt[t][cc];
      #pragma unroll
      for(int p=0;p<PB;p++) acc[p] += xs[p][c0+cc]*wv;
    }
  }
  #pragma unroll
  for(int p=0;p<PB;p++) o[(rem0+p)*DIN + t] = acc[p];
}

// ---------------- K2: depthwise 3x3 conv (SAME, zero pad) + bias + SiLU ----
__global__ __launch_bounds__(DIN) void conv_kernel(
    const float* __restrict__ xproj_r, const float* __restrict__ xproj_e,
    const float* __restrict__ cw_r, const float* __restrict__ cb_r,
    const float* __restrict__ cw_e, const float* __restrict__ cb_e,
    float* __restrict__ xconv_r, float* __restrict__ xconv_e){
  int blk = blockIdx.x;
  int m = blk / NPOS; int rem = blk % NPOS;
  int b = rem / LL, p = rem % LL;
  int y = p >> 6, x = p & 63;           // p = y*WW + x
  const float* in = (m ? xproj_e : xproj_r) + (size_t)b*LL*DIN;
  const float* cw = m ? cw_e : cw_r;
  const float* cb = m ? cb_e : cb_r;
  float* out = m ? xconv_e : xconv_r;
  int d = threadIdx.x;
  float acc = cb[d];
  #pragma unroll
  for(int dy=-1;dy<=1;dy++){
    int yy = y+dy; if(yy<0 || yy>=HH) continue;
    #pragma unroll
    for(int dx=-1;dx<=1;dx++){
      int xx = x+dx; if(xx<0 || xx>=WW) continue;
      acc += in[(size_t)(yy*WW+xx)*DIN + d] * cw[d*9 + (dy+1)*3 + (dx+1)];
    }
  }
  float s = acc / (1.f + __expf(-acc));  // silu
  out[(size_t)(b*LL+p)*DIN + d] = s;
}

// -------- K3: x_proj as LDS-tiled mini-GEMM over canonical positions -------
// For each canonical position p, compute all 56 outputs (k in [0,4), c in [0,14))
// = dot(xconv[b,p,:], xpw[k*14+c,:]), then scatter to dtBC[b][k][l_k(p)][c]
// where l_k is the inverse scan map. Removes the map_pos gather and the 14x
// redundant row reads of the old version.
#define TPOS 32               // positions per block
__global__ __launch_bounds__(256) void projbc_kernel(
    const float* __restrict__ xconv_r, const float* __restrict__ xconv_e,
    const float* __restrict__ xpw,
    float* __restrict__ dtBC_r, float* __restrict__ dtBC_e){
  int blk = blockIdx.x;                 // m*(BB*LL/TPOS) + b*(LL/TPOS) + tile
  int m = blk / (BB*LL/TPOS); int rem = blk % (BB*LL/TPOS);
  int b = rem / (LL/TPOS); int p0 = (rem % (LL/TPOS)) * TPOS;
  const float* xc = (m ? xconv_e : xconv_r) + ((size_t)b*LL + p0)*DIN;
  float* o = (m ? dtBC_e : dtBC_r) + (size_t)b*KK*LL*14;

  // stride-97 rows: 97%32==1 -> bank(p*97+d)=(p+d)%32, conflict-free
  __shared__ float xs[TPOS*97];         // 32 pos x 96 d-tile
  __shared__ float wsd[56*97];          // 56 cbar x 96 d-tile

  int t = threadIdx.x;
  int g = t >> 5;                       // 0..7 : handles cbar = g*7 .. g*7+6
  int pl = t & 31;                      // position within tile

  float acc[7];
  #pragma unroll
  for(int j=0;j<7;j++) acc[j]=0.f;

  for(int dt0=0; dt0<DIN; dt0+=96){
    __syncthreads();
    for(int idx=t; idx<TPOS*96; idx+=256){
      int r = idx/96, ccol = idx%96;
      xs[r*97+ccol] = xc[(size_t)r*DIN + dt0 + ccol];
    }
    for(int idx=t; idx<56*96; idx+=256){
      int r = idx/96, ccol = idx%96;
      wsd[r*97+ccol] = xpw[(size_t)r*DIN + dt0 + ccol];
    }
    __syncthreads();
    const float* xrow = &xs[pl*97];
    #pragma unroll 4
    for(int d=0; d<96; d++){
      float xv = xrow[d];
      #pragma unroll
      for(int j=0;j<7;j++) acc[j] += wsd[(g*7+j)*97 + d]*xv;
    }
  }

  int p = p0 + pl;
  int ptr_ = (p&63)*64 + (p>>6);        // inverse of the transpose map
  #pragma unroll
  for(int j=0;j<7;j++){
    int cbar = g*7+j;
    int k = cbar/14, c = cbar%14;
    int l = (k==0) ? p : (k==1) ? ptr_ : (k==2) ? (LL-1-p) : (LL-1-ptr_);
    o[((size_t)k*LL + l)*14 + c] = acc[j];
  }
}

// ------- K4a: per-chunk local scan -> (end state S, sum of dt) -------------
__global__ __launch_bounds__(DIN) void scan_p1_kernel(
    const float* __restrict__ xconv_r, const float* __restrict__ xconv_e,
    const float* __restrict__ dtBC_r, const float* __restrict__ dtBC_e,
    const float* __restrict__ dtw, const float* __restrict__ dtb,
    const float* __restrict__ A_logs,
    float* __restrict__ trans_S, float* __restrict__ sumdt){
  int ch = blockIdx.x / NCHUNK;         // m*16 + b*4 + k
  int cidx = blockIdx.x % NCHUNK;
  int m = ch >> 4, b = (ch>>2)&3, k = ch&3;
  int d = threadIdx.x;
  int l0 = cidx*CLEN;

  float A[NS], Wd[RR];
  #pragma unroll
  for(int n=0;n<NS;n++) A[n] = -__expf(A_logs[(size_t)(k*DIN+d)*NS + n]);
  #pragma unroll
  for(int r=0;r<RR;r++) Wd[r] = dtw[((size_t)k*DIN + d)*RR + r];
  float bias = dtb[k*DIN+d];

  const float* xc    = (m ? xconv_e : xconv_r) + (size_t)b*LL*DIN;
  const float* dbc_m = (m ? dtBC_e : dtBC_r) + ((size_t)b*KK + k)*LL*14;

  __shared__ float db_s[CLEN][14];
  for(int idx=threadIdx.x; idx<CLEN*14; idx+=DIN)
    db_s[idx/14][idx%14] = dbc_m[(size_t)l0*14 + idx];
  __syncthreads();

  float h0=0.f,h1=0.f,h2=0.f,h3=0.f,sd=0.f;
  for(int i=0;i<CLEN;i++){
    float dtr = bias;
    #pragma unroll
    for(int r=0;r<RR;r++) dtr += db_s[i][r]*Wd[r];
    float dt = fmaxf(dtr,0.f) + log1pf(__expf(-fabsf(dtr)));
    sd += dt;
    float u = xc[(size_t)map_pos(k, l0+i)*DIN + d];
    float dtu = dt*u;
    h0 = h0*__expf(dt*A[0]) + dtu*db_s[i][6];
    h1 = h1*__expf(dt*A[1]) + dtu*db_s[i][7];
    h2 = h2*__expf(dt*A[2]) + dtu*db_s[i][8];
    h3 = h3*__expf(dt*A[3]) + dtu*db_s[i][9];
  }
  size_t base = ((size_t)(ch*NCHUNK + cidx)*NS)*DIN + d;
  trans_S[base          ] = h0;
  trans_S[base +   DIN  ] = h1;
  trans_S[base + 2*DIN  ] = h2;
  trans_S[base + 3*DIN  ] = h3;
  sumdt[(size_t)(ch*NCHUNK + cidx)*DIN + d] = sd;
}

// ------- K4b: sequential inter-chunk scan -> entering state per chunk ------
__global__ __launch_bounds__(DIN) void scan_p2_kernel(
    const float* __restrict__ trans_S, const float* __restrict__ sumdt,
    const float* __restrict__ A_logs, float* __restrict__ hin){
  int ch = blockIdx.x; int k = ch & 3; int d = threadIdx.x;
  float A[NS];
  #pragma unroll
  for(int n=0;n<NS;n++) A[n] = -__expf(A_logs[(size_t)(k*DIN+d)*NS + n]);
  float h[NS] = {0.f,0.f,0.f,0.f};
  for(int c=0;c<NCHUNK;c++){
    size_t base = ((size_t)(ch*NCHUNK + c)*NS)*DIN + d;
    #pragma unroll
    for(int n=0;n<NS;n++) hin[base + (size_t)n*DIN] = h[n];
    float sd = sumdt[(size_t)(ch*NCHUNK + c)*DIN + d];
    #pragma unroll
    for(int n=0;n<NS;n++) h[n] = h[n]*__expf(A[n]*sd) + trans_S[base + (size_t)n*DIN];
  }
}

// ------- K4c: per-chunk scan with true entering state -> y (merged) --------
__global__ __launch_bounds__(DIN) void scan_p3_kernel(
    const float* __restrict__ xconv_r, const float* __restrict__ xconv_e,
    const float* __restrict__ dtBC_r, const float* __restrict__ dtBC_e,
    const float* __restrict__ dtw, const float* __restrict__ dtb,
    const float* __restrict__ A_logs, const float* __restrict__ Ds,
    const float* __restrict__ hin,
    float* __restrict__ ym_r, float* __restrict__ ym_e){
  int ch = blockIdx.x / NCHUNK;
  int cidx = blockIdx.x % NCHUNK;
  int m = ch >> 4, b = (ch>>2)&3, k = ch&3;
  int d = threadIdx.x;
  int l0 = cidx*CLEN;

  float A[NS], Wd[RR];
  #pragma unroll
  for(int n=0;n<NS;n++) A[n] = -__expf(A_logs[(size_t)(k*DIN+d)*NS + n]);
  #pragma unroll
  for(int r=0;r<RR;r++) Wd[r] = dtw[((size_t)k*DIN + d)*RR + r];
  float bias = dtb[k*DIN+d];
  float Dv = Ds[k*DIN+d];

  const float* xc    = (m ? xconv_e : xconv_r) + (size_t)b*LL*DIN;
  const float* dbc_m = (m ? dtBC_e : dtBC_r) + ((size_t)b*KK + k)*LL*14;  // dt,B: own modality
  const float* dbc_o = (m ? dtBC_r : dtBC_e) + ((size_t)b*KK + k)*LL*14;  // C: other modality
  float* ym = (m ? ym_e : ym_r) + (size_t)b*LL*DIN;

  __shared__ float db_s[CLEN][14];
  __shared__ float c_s[CLEN][NS];
  for(int idx=threadIdx.x; idx<CLEN*14; idx+=DIN)
    db_s[idx/14][idx%14] = dbc_m[(size_t)l0*14 + idx];
  for(int idx=threadIdx.x; idx<CLEN*NS; idx+=DIN){
    int i = idx>>2, j = idx&3;
    c_s[i][j] = dbc_o[(size_t)(l0+i)*14 + 10 + j];
  }
  __syncthreads();

  size_t hbase = ((size_t)(ch*NCHUNK + cidx)*NS)*DIN + d;
  float h0=hin[hbase], h1=hin[hbase+DIN], h2=hin[hbase+2*DIN], h3=hin[hbase+3*DIN];

  for(int i=0;i<CLEN;i++){
    float dtr = bias;
    #pragma unroll
    for(int r=0;r<RR;r++) dtr += db_s[i][r]*Wd[r];
    float dt = fmaxf(dtr,0.f) + log1pf(__expf(-fabsf(dtr)));
    int pos = map_pos(k, l0+i);
    float u = xc[(size_t)pos*DIN + d];
    float dtu = dt*u;
    h0 = h0*__expf(dt*A[0]) + dtu*db_s[i][6];
    h1 = h1*__expf(dt*A[1]) + dtu*db_s[i][7];
    h2 = h2*__expf(dt*A[2]) + dtu*db_s[i][8];
    h3 = h3*__expf(dt*A[3]) + dtu*db_s[i][9];
    float y = h0*c_s[i][0] + h1*c_s[i][1] + h2*c_s[i][2] + h3*c_s[i][3] + Dv*u;
    atomicAdd(&ym[(size_t)pos*DIN + d], y);
  }
}

// ---------------- K5: LayerNorm(192) + out_proj(192->96) + residual --------
__global__ __launch_bounds__(DIN) void ln_out_kernel(
    const float* __restrict__ ym_r, const float* __restrict__ ym_e,
    const float* __restrict__ ln_rg, const float* __restrict__ ln_rb,
    const float* __restrict__ ln_eg, const float* __restrict__ ln_eb,
    const float* __restrict__ opw_r, const float* __restrict__ opw_e,
    const float* __restrict__ x_rgb, const float* __restrict__ x_e,
    float* __restrict__ out){
  int blk = blockIdx.x;                 // m*(NPOS/PB) + g
  int m = blk / (NPOS/PB); int g = blk % (NPOS/PB);
  size_t rem0 = (size_t)g * PB;
  const float* ym = (m ? ym_e : ym_r) + rem0*DIN;
  int t = threadIdx.x;
  int wid = t>>6;

  float v[PB];
  #pragma unroll
  for(int p=0;p<PB;p++) v[p] = ym[(size_t)p*DIN + t];

  __shared__ float red_s[PB][3], red_q[PB][3];
  #pragma unroll
  for(int p=0;p<PB;p++){
    float s = v[p], q = v[p]*v[p];
    #pragma unroll
    for(int off=32; off>0; off>>=1){ s += __shfl_down(s,off); q += __shfl_down(q,off); }
    if((t&63)==0){ red_s[p][wid]=s; red_q[p][wid]=q; }
  }
  __syncthreads();

  const float* gg = m ? ln_eg : ln_rg;
  const float* be = m ? ln_eb : ln_rb;
  __shared__ float yn_s[PB][DIN];
  float gv = gg[t], bv = be[t];
  #pragma unroll
  for(int p=0;p<PB;p++){
    float S = red_s[p][0]+red_s[p][1]+red_s[p][2];
    float Q = red_q[p][0]+red_q[p][1]+red_q[p][2];
    float mu  = S*(1.f/DIN);
    float var = Q*(1.f/DIN) - mu*mu;
    float inv = rsqrtf(var + 1e-5f);
    yn_s[p][t] = (v[p]-mu)*inv*gv + bv;
  }
  __syncthreads();

  // out-proj: thread t -> c = t%96, positions {t/96, t/96+2, t/96+4, t/96+6}
  int c = t % CC;
  int pbase = t / CC;                    // 0 or 1
  const float* w = (m ? opw_e : opw_r) + (size_t)c*DIN;
  float acc[4] = {0.f,0.f,0.f,0.f};
  for(int dd=0; dd<DIN; dd++){
    float wv = w[dd];
    #pragma unroll
    for(int pp=0;pp<4;pp++) acc[pp] += yn_s[pbase + 2*pp][dd]*wv;
  }
  const float* xin = m ? x_e : x_rgb;
  #pragma unroll
  for(int pp=0;pp<4;pp++){
    size_t rem = rem0 + pbase + 2*pp;
    size_t oi = (size_t)m*NPOS*CC + rem*CC + c;
    out[oi] = acc[pp] + xin[rem*CC + c];
  }
}

extern "C" void kernel_launch(void* const* d_in, const int* in_sizes, int n_in,
                              void* d_out, int out_size, void* d_ws, size_t ws_size,
                              hipStream_t stream){
  const float* x_rgb = (const float*)d_in[0];
  const float* x_e   = (const float*)d_in[1];
  const float* ipw_r = (const float*)d_in[2];
  const float* ipw_e = (const float*)d_in[3];
  const float* cw_r  = (const float*)d_in[4];
  const float* cb_r  = (const float*)d_in[5];
  const float* cw_e  = (const float*)d_in[6];
  const float* cb_e  = (const float*)d_in[7];
  const float* xpw   = (const float*)d_in[8];
  const float* dtw   = (const float*)d_in[9];
  const float* dtb   = (const float*)d_in[10];
  const float* Alog  = (const float*)d_in[11];
  const float* Ds_   = (const float*)d_in[12];
  const float* ln_rg = (const float*)d_in[13];
  const float* ln_rb = (const float*)d_in[14];
  const float* ln_eg = (const float*)d_in[15];
  const float* ln_eb = (const float*)d_in[16];
  const float* opw_r = (const float*)d_in[17];
  const float* opw_e = (const float*)d_in[18];
  float* out = (float*)d_out;

  float* ws = (float*)d_ws;
  float* xproj_r = ws;
  float* xproj_e = ws + NPD;
  float* xconv_r = ws + 2*NPD;
  float* xconv_e = ws + 3*NPD;
  float* dtBC_r  = ws + 4*NPD;
  float* dtBC_e  = ws + 4*NPD + NDBC;
  float* trans_S = ws + 4*NPD + 2*NDBC;                         // NCHAIN*NCHUNK*NS*DIN
  float* sumdt   = trans_S + (size_t)NCHAIN*NCHUNK*NS*DIN;      // NCHAIN*NCHUNK*DIN
  float* hin     = sumdt   + (size_t)NCHAIN*NCHUNK*DIN;         // NCHAIN*NCHUNK*NS*DIN
  float* ym_r = xproj_r;   // xproj dead after conv
  float* ym_e = xproj_e;

  inproj_kernel<<<2*NPOS/PB, DIN, 0, stream>>>(x_rgb, x_e, ipw_r, ipw_e, xproj_r, xproj_e);
  conv_kernel<<<2*NPOS, DIN, 0, stream>>>(xproj_r, xproj_e, cw_r, cb_r, cw_e, cb_e, xconv_r, xconv_e);
  projbc_kernel<<<2*BB*(LL/TPOS), 256, 0, stream>>>(xconv_r, xconv_e, xpw, dtBC_r, dtBC_e);
  scan_p1_kernel<<<NCHAIN*NCHUNK, DIN, 0, stream>>>(xconv_r, xconv_e, dtBC_r, dtBC_e,
                                                    dtw, dtb, Alog, trans_S, sumdt);
  scan_p2_kernel<<<NCHAIN, DIN, 0, stream>>>(trans_S, sumdt, Alog, hin);
  hipMemsetAsync(ym_r, 0, 2*NPD*sizeof(float), stream);  // zero merge accumulators (after conv: xproj dead)
  scan_p3_kernel<<<NCHAIN*NCHUNK, DIN, 0, stream>>>(xconv_r, xconv_e, dtBC_r, dtBC_e,
                                                    dtw, dtb, Alog, Ds_, hin, ym_r, ym_e);
  ln_out_kernel<<<2*NPOS/PB, DIN, 0, stream>>>(ym_r, ym_e, ln_rg, ln_rb, ln_eg, ln_eb,
                                               opw_r, opw_e, x_rgb, x_e, out);
}

// Round 8
// 463.264 us; speedup vs baseline: 8.5297x; 1.1746x over previous
//
#include <hip/hip_runtime.h>

#define BB 4
#define HH 64
#define WW 64
#define CC 96
#define DIN 192
#define NS 4
#define RR 6
#define KK 4
#define LL 4096               // HH*WW
#define NPOS (BB*LL)          // 16384 positions per modality
#define NPD ((size_t)NPOS*DIN)
#define NDBC ((size_t)BB*KK*LL*14)
#define NCHUNK 128
#define CLEN 32               // NCHUNK*CLEN == LL ; CLEN must divide 64
#define NCHAIN 32             // 2 mods * 4 b * 4 k
#define PB 8                  // positions per block in inproj/ln_out

// canonical spatial position for scan-direction k at scan step l
__device__ __forceinline__ int map_pos(int k, int l){
  switch(k){
    case 0: return l;
    case 1: { int wi=l>>6, hi=l&63; return hi*WW+wi; }     // (w,h) flatten -> h*W+w
    case 2: return LL-1-l;
    default:{ int lr=LL-1-l; int wi=lr>>6, hi=lr&63; return hi*WW+wi; }
  }
}
// within a chunk [l0, l0+CLEN) with CLEN | 64, pos is affine: pos = map_pos(k,l0) + i*stride
__device__ __forceinline__ int pos_stride(int k){
  return (k==0) ? 1 : (k==1) ? WW : (k==2) ? -1 : -WW;
}

// ---------------- K1: in_proj (bhwc,dc->bhwd), 8 positions per block -------
__global__ __launch_bounds__(DIN) void inproj_kernel(
    const float* __restrict__ x_rgb, const float* __restrict__ x_e,
    const float* __restrict__ w_r,   const float* __restrict__ w_e,
    float* __restrict__ xproj_r,    float* __restrict__ xproj_e){
  int blk = blockIdx.x;                 // m*(NPOS/PB) + g
  int m = blk / (NPOS/PB); int g = blk % (NPOS/PB);
  size_t rem0 = (size_t)g * PB;
  const float* x = m ? x_e : x_rgb;
  const float* w = m ? w_e : w_r;
  float* o = m ? xproj_e : xproj_r;
  __shared__ float xs[PB][CC];
  __shared__ float wt[DIN][17];         // 16 cols + pad
  int t = threadIdx.x;
  for(int idx=t; idx<PB*CC; idx+=DIN) xs[idx/CC][idx%CC] = x[rem0*CC + idx];
  float acc[PB];
  #pragma unroll
  for(int p=0;p<PB;p++) acc[p]=0.f;
  for(int c0=0; c0<CC; c0+=16){
    __syncthreads();
    for(int idx=t; idx<DIN*16; idx+=DIN){
      int dd = idx>>4, cc = idx&15;
      wt[dd][cc] = w[(size_t)dd*CC + c0 + cc];
    }
    __syncthreads();
    #pragma unroll
    for(int cc=0; cc<16; cc++){
      float wv = wt[t][cc];
      #pragma unroll
      for(int p=0;p<PB;p++) acc[p] += xs[p][c0+cc]*wv;
    }
  }
  #pragma unroll
  for(int p=0;p<PB;p++) o[(rem0+p)*DIN + t] = acc[p];
}

// ---------------- K2: depthwise 3x3 conv (SAME, zero pad) + bias + SiLU ----
__global__ __launch_bounds__(DIN) void conv_kernel(
    const float* __restrict__ xproj_r, const float* __restrict__ xproj_e,
    const float* __restrict__ cw_r, const float* __restrict__ cb_r,
    const float* __restrict__ cw_e, const float* __restrict__ cb_e,
    float* __restrict__ xconv_r, float* __restrict__ xconv_e){
  int blk = blockIdx.x;
  int m = blk / NPOS; int rem = blk % NPOS;
  int b = rem / LL, p = rem % LL;
  int y = p >> 6, x = p & 63;           // p = y*WW + x
  const float* in = (m ? xproj_e : xproj_r) + (size_t)b*LL*DIN;
  const float* cw = m ? cw_e : cw_r;
  const float* cb = m ? cb_e : cb_r;
  float* out = m ? xconv_e : xconv_r;
  int d = threadIdx.x;
  float acc = cb[d];
  #pragma unroll
  for(int dy=-1;dy<=1;dy++){
    int yy = y+dy; if(yy<0 || yy>=HH) continue;
    #pragma unroll
    for(int dx=-1;dx<=1;dx++){
      int xx = x+dx; if(xx<0 || xx>=WW) continue;
      acc += in[(size_t)(yy*WW+xx)*DIN + d] * cw[d*9 + (dy+1)*3 + (dx+1)];
    }
  }
  float s = acc / (1.f + __expf(-acc));  // silu
  out[(size_t)(b*LL+p)*DIN + d] = s;
}

// -------- K3: x_proj as LDS-tiled mini-GEMM over canonical positions -------
#define TPOS 32               // positions per block
__global__ __launch_bounds__(256) void projbc_kernel(
    const float* __restrict__ xconv_r, const float* __restrict__ xconv_e,
    const float* __restrict__ xpw,
    float* __restrict__ dtBC_r, float* __restrict__ dtBC_e){
  int blk = blockIdx.x;                 // m*(BB*LL/TPOS) + b*(LL/TPOS) + tile
  int m = blk / (BB*LL/TPOS); int rem = blk % (BB*LL/TPOS);
  int b = rem / (LL/TPOS); int p0 = (rem % (LL/TPOS)) * TPOS;
  const float* xc = (m ? xconv_e : xconv_r) + ((size_t)b*LL + p0)*DIN;
  float* o = (m ? dtBC_e : dtBC_r) + (size_t)b*KK*LL*14;

  // stride-97 rows: 97%32==1 -> bank(p*97+d)=(p+d)%32, conflict-free
  __shared__ float xs[TPOS*97];         // 32 pos x 96 d-tile
  __shared__ float wsd[56*97];          // 56 cbar x 96 d-tile

  int t = threadIdx.x;
  int g = t >> 5;                       // 0..7 : handles cbar = g*7 .. g*7+6
  int pl = t & 31;                      // position within tile

  float acc[7];
  #pragma unroll
  for(int j=0;j<7;j++) acc[j]=0.f;

  for(int dt0=0; dt0<DIN; dt0+=96){
    __syncthreads();
    for(int idx=t; idx<TPOS*96; idx+=256){
      int r = idx/96, ccol = idx%96;
      xs[r*97+ccol] = xc[(size_t)r*DIN + dt0 + ccol];
    }
    for(int idx=t; idx<56*96; idx+=256){
      int r = idx/96, ccol = idx%96;
      wsd[r*97+ccol] = xpw[(size_t)r*DIN + dt0 + ccol];
    }
    __syncthreads();
    const float* xrow = &xs[pl*97];
    #pragma unroll 4
    for(int d=0; d<96; d++){
      float xv = xrow[d];
      #pragma unroll
      for(int j=0;j<7;j++) acc[j] += wsd[(g*7+j)*97 + d]*xv;
    }
  }

  int p = p0 + pl;
  int ptr_ = (p&63)*64 + (p>>6);        // inverse of the transpose map
  #pragma unroll
  for(int j=0;j<7;j++){
    int cbar = g*7+j;
    int k = cbar/14, c = cbar%14;
    int l = (k==0) ? p : (k==1) ? ptr_ : (k==2) ? (LL-1-p) : (LL-1-ptr_);
    o[((size_t)k*LL + l)*14 + c] = acc[j];
  }
}

// db4 row layout (16 floats): [0-3]=B, [4-7]=C(p3 only), [8-13]=dtl, [14-15]=pad
// ------- K4a: per-chunk local scan -> (end state S, sum of dt) -------------
__global__ __launch_bounds__(DIN) void scan_p1_kernel(
    const float* __restrict__ xconv_r, const float* __restrict__ xconv_e,
    const float* __restrict__ dtBC_r, const float* __restrict__ dtBC_e,
    const float* __restrict__ dtw, const float* __restrict__ dtb,
    const float* __restrict__ A_logs,
    float* __restrict__ trans_S, float* __restrict__ sumdt){
  int ch = blockIdx.x / NCHUNK;         // m*16 + b*4 + k
  int cidx = blockIdx.x % NCHUNK;
  int m = ch >> 4, b = (ch>>2)&3, k = ch&3;
  int d = threadIdx.x;
  int l0 = cidx*CLEN;

  float4 al = *(const float4*)&A_logs[(size_t)(k*DIN+d)*NS];
  float A0=-__expf(al.x), A1=-__expf(al.y), A2=-__expf(al.z), A3=-__expf(al.w);
  float Wd[RR];
  #pragma unroll
  for(int r=0;r<RR;r++) Wd[r] = dtw[((size_t)k*DIN + d)*RR + r];
  float bias = dtb[k*DIN+d];

  const float* xc    = (m ? xconv_e : xconv_r) + (size_t)b*LL*DIN;
  const float* dbc_m = (m ? dtBC_e : dtBC_r) + ((size_t)b*KK + k)*LL*14;

  __shared__ float4 db4[CLEN][4];
  __shared__ float u_s[CLEN*DIN];
  float* dbf = (float*)db4;

  for(int idx=d; idx<CLEN*14; idx+=DIN){
    int i = idx/14, j = idx%14;
    int slot = (j<6) ? (8+j) : (j-6);
    dbf[i*16+slot] = dbc_m[(size_t)l0*14 + idx];
  }
  int stride = pos_stride(k);
  int pos0 = map_pos(k, l0);
  #pragma unroll 8
  for(int i=0;i<CLEN;i++)
    u_s[i*DIN+d] = xc[(size_t)(pos0+i*stride)*DIN + d];
  __syncthreads();

  float h0=0.f,h1=0.f,h2=0.f,h3=0.f,sd=0.f;
  #pragma unroll 4
  for(int i=0;i<CLEN;i++){
    float4 Bv  = db4[i][0];
    float4 d03 = db4[i][2];
    float4 d45 = db4[i][3];
    float dtr = fmaf(d03.x,Wd[0], fmaf(d03.y,Wd[1], fmaf(d03.z,Wd[2],
                fmaf(d03.w,Wd[3], fmaf(d45.x,Wd[4], fmaf(d45.y,Wd[5], bias))))));
    float dt = fmaxf(dtr,0.f) + __logf(1.f + __expf(-fabsf(dtr)));
    sd += dt;
    float u = u_s[i*DIN + d];
    float dtu = dt*u;
    h0 = fmaf(h0, __expf(dt*A0), dtu*Bv.x);
    h1 = fmaf(h1, __expf(dt*A1), dtu*Bv.y);
    h2 = fmaf(h2, __expf(dt*A2), dtu*Bv.z);
    h3 = fmaf(h3, __expf(dt*A3), dtu*Bv.w);
  }
  size_t base = ((size_t)(ch*NCHUNK + cidx)*NS)*DIN + d;
  trans_S[base          ] = h0;
  trans_S[base +   DIN  ] = h1;
  trans_S[base + 2*DIN  ] = h2;
  trans_S[base + 3*DIN  ] = h3;
  sumdt[(size_t)(ch*NCHUNK + cidx)*DIN + d] = sd;
}

// ------- K4b: sequential inter-chunk scan -> entering state per chunk ------
__global__ __launch_bounds__(DIN) void scan_p2_kernel(
    const float* __restrict__ trans_S, const float* __restrict__ sumdt,
    const float* __restrict__ A_logs, float* __restrict__ hin){
  int ch = blockIdx.x; int k = ch & 3; int d = threadIdx.x;
  float4 al = *(const float4*)&A_logs[(size_t)(k*DIN+d)*NS];
  float A[NS] = {-__expf(al.x), -__expf(al.y), -__expf(al.z), -__expf(al.w)};
  float h[NS] = {0.f,0.f,0.f,0.f};
  for(int c0=0;c0<NCHUNK;c0+=4){
    float S[4][NS], sdv[4];
    #pragma unroll
    for(int cc=0;cc<4;cc++){
      size_t base = ((size_t)(ch*NCHUNK + c0+cc)*NS)*DIN + d;
      #pragma unroll
      for(int n=0;n<NS;n++) S[cc][n] = trans_S[base + (size_t)n*DIN];
      sdv[cc] = sumdt[(size_t)(ch*NCHUNK + c0+cc)*DIN + d];
    }
    #pragma unroll
    for(int cc=0;cc<4;cc++){
      size_t base = ((size_t)(ch*NCHUNK + c0+cc)*NS)*DIN + d;
      #pragma unroll
      for(int n=0;n<NS;n++) hin[base + (size_t)n*DIN] = h[n];
      #pragma unroll
      for(int n=0;n<NS;n++) h[n] = fmaf(h[n], __expf(A[n]*sdv[cc]), S[cc][n]);
    }
  }
}

// ------- K4c: per-chunk scan with true entering state -> y (merged) --------
__global__ __launch_bounds__(DIN) void scan_p3_kernel(
    const float* __restrict__ xconv_r, const float* __restrict__ xconv_e,
    const float* __restrict__ dtBC_r, const float* __restrict__ dtBC_e,
    const float* __restrict__ dtw, const float* __restrict__ dtb,
    const float* __restrict__ A_logs, const float* __restrict__ Ds,
    const float* __restrict__ hin,
    float* __restrict__ ym_r, float* __restrict__ ym_e){
  int ch = blockIdx.x / NCHUNK;
  int cidx = blockIdx.x % NCHUNK;
  int m = ch >> 4, b = (ch>>2)&3, k = ch&3;
  int d = threadIdx.x;
  int l0 = cidx*CLEN;

  float4 al = *(const float4*)&A_logs[(size_t)(k*DIN+d)*NS];
  float A0=-__expf(al.x), A1=-__expf(al.y), A2=-__expf(al.z), A3=-__expf(al.w);
  float Wd[RR];
  #pragma unroll
  for(int r=0;r<RR;r++) Wd[r] = dtw[((size_t)k*DIN + d)*RR + r];
  float bias = dtb[k*DIN+d];
  float Dv = Ds[k*DIN+d];

  const float* xc    = (m ? xconv_e : xconv_r) + (size_t)b*LL*DIN;
  const float* dbc_m = (m ? dtBC_e : dtBC_r) + ((size_t)b*KK + k)*LL*14;  // dt,B: own modality
  const float* dbc_o = (m ? dtBC_r : dtBC_e) + ((size_t)b*KK + k)*LL*14;  // C: other modality
  float* ym = (m ? ym_e : ym_r) + (size_t)b*LL*DIN;

  __shared__ float4 db4[CLEN][4];
  __shared__ float u_s[CLEN*DIN];
  float* dbf = (float*)db4;

  for(int idx=d; idx<CLEN*14; idx+=DIN){
    int i = idx/14, j = idx%14;
    int slot = (j<6) ? (8+j) : (j-6);
    dbf[i*16+slot] = dbc_m[(size_t)l0*14 + idx];
  }
  for(int idx=d; idx<CLEN*NS; idx+=DIN){
    int i = idx>>2, j = idx&3;
    dbf[i*16 + 4 + j] = dbc_o[(size_t)(l0+i)*14 + 10 + j];
  }
  int stride = pos_stride(k);
  int pos0 = map_pos(k, l0);
  #pragma unroll 8
  for(int i=0;i<CLEN;i++)
    u_s[i*DIN+d] = xc[(size_t)(pos0+i*stride)*DIN + d];
  __syncthreads();

  size_t hbase = ((size_t)(ch*NCHUNK + cidx)*NS)*DIN + d;
  float h0=hin[hbase], h1=hin[hbase+DIN], h2=hin[hbase+2*DIN], h3=hin[hbase+3*DIN];

  #pragma unroll 4
  for(int i=0;i<CLEN;i++){
    float4 Bv  = db4[i][0];
    float4 Cv  = db4[i][1];
    float4 d03 = db4[i][2];
    float4 d45 = db4[i][3];
    float dtr = fmaf(d03.x,Wd[0], fmaf(d03.y,Wd[1], fmaf(d03.z,Wd[2],
                fmaf(d03.w,Wd[3], fmaf(d45.x,Wd[4], fmaf(d45.y,Wd[5], bias))))));
    float dt = fmaxf(dtr,0.f) + __logf(1.f + __expf(-fabsf(dtr)));
    float u = u_s[i*DIN + d];
    float dtu = dt*u;
    h0 = fmaf(h0, __expf(dt*A0), dtu*Bv.x);
    h1 = fmaf(h1, __expf(dt*A1), dtu*Bv.y);
    h2 = fmaf(h2, __expf(dt*A2), dtu*Bv.z);
    h3 = fmaf(h3, __expf(dt*A3), dtu*Bv.w);
    float y = fmaf(h0,Cv.x, fmaf(h1,Cv.y, fmaf(h2,Cv.z, fmaf(h3,Cv.w, Dv*u))));
    atomicAdd(&ym[(size_t)(pos0+i*stride)*DIN + d], y);
  }
}

// ---------------- K5: LayerNorm(192) + out_proj(192->96) + residual --------
__global__ __launch_bounds__(DIN) void ln_out_kernel(
    const float* __restrict__ ym_r, const float* __restrict__ ym_e,
    const float* __restrict__ ln_rg, const float* __restrict__ ln_rb,
    const float* __restrict__ ln_eg, const float* __restrict__ ln_eb,
    const float* __restrict__ opw_r, const float* __restrict__ opw_e,
    const float* __restrict__ x_rgb, const float* __restrict__ x_e,
    float* __restrict__ out){
  int blk = blockIdx.x;                 // m*(NPOS/PB) + g
  int m = blk / (NPOS/PB); int g = blk % (NPOS/PB);
  size_t rem0 = (size_t)g * PB;
  const float* ym = (m ? ym_e : ym_r) + rem0*DIN;
  int t = threadIdx.x;
  int wid = t>>6;

  float v[PB];
  #pragma unroll
  for(int p=0;p<PB;p++) v[p] = ym[(size_t)p*DIN + t];

  __shared__ float red_s[PB][3], red_q[PB][3];
  #pragma unroll
  for(int p=0;p<PB;p++){
    float s = v[p], q = v[p]*v[p];
    #pragma unroll
    for(int off=32; off>0; off>>=1){ s += __shfl_down(s,off); q += __shfl_down(q,off); }
    if((t&63)==0){ red_s[p][wid]=s; red_q[p][wid]=q; }
  }
  __syncthreads();

  const float* gg = m ? ln_eg : ln_rg;
  const float* be = m ? ln_eb : ln_rb;
  __shared__ float yn_s[PB][DIN];
  float gv = gg[t], bv = be[t];
  #pragma unroll
  for(int p=0;p<PB;p++){
    float S = red_s[p][0]+red_s[p][1]+red_s[p][2];
    float Q = red_q[p][0]+red_q[p][1]+red_q[p][2];
    float mu  = S*(1.f/DIN);
    float var = Q*(1.f/DIN) - mu*mu;
    float inv = rsqrtf(var + 1e-5f);
    yn_s[p][t] = (v[p]-mu)*inv*gv + bv;
  }
  __syncthreads();

  // out-proj: thread t -> c = t%96, positions {t/96, t/96+2, t/96+4, t/96+6}
  int c = t % CC;
  int pbase = t / CC;                    // 0 or 1
  const float* w = (m ? opw_e : opw_r) + (size_t)c*DIN;
  float acc[4] = {0.f,0.f,0.f,0.f};
  for(int dd=0; dd<DIN; dd++){
    float wv = w[dd];
    #pragma unroll
    for(int pp=0;pp<4;pp++) acc[pp] += yn_s[pbase + 2*pp][dd]*wv;
  }
  const float* xin = m ? x_e : x_rgb;
  #pragma unroll
  for(int pp=0;pp<4;pp++){
    size_t rem = rem0 + pbase + 2*pp;
    size_t oi = (size_t)m*NPOS*CC + rem*CC + c;
    out[oi] = acc[pp] + xin[rem*CC + c];
  }
}

extern "C" void kernel_launch(void* const* d_in, const int* in_sizes, int n_in,
                              void* d_out, int out_size, void* d_ws, size_t ws_size,
                              hipStream_t stream){
  const float* x_rgb = (const float*)d_in[0];
  const float* x_e   = (const float*)d_in[1];
  const float* ipw_r = (const float*)d_in[2];
  const float* ipw_e = (const float*)d_in[3];
  const float* cw_r  = (const float*)d_in[4];
  const float* cb_r  = (const float*)d_in[5];
  const float* cw_e  = (const float*)d_in[6];
  const float* cb_e  = (const float*)d_in[7];
  const float* xpw   = (const float*)d_in[8];
  const float* dtw   = (const float*)d_in[9];
  const float* dtb   = (const float*)d_in[10];
  const float* Alog  = (const float*)d_in[11];
  const float* Ds_   = (const float*)d_in[12];
  const float* ln_rg = (const float*)d_in[13];
  const float* ln_rb = (const float*)d_in[14];
  const float* ln_eg = (const float*)d_in[15];
  const float* ln_eb = (const float*)d_in[16];
  const float* opw_r = (const float*)d_in[17];
  const float* opw_e = (const float*)d_in[18];
  float* out = (float*)d_out;

  float* ws = (float*)d_ws;
  float* xproj_r = ws;
  float* xproj_e = ws + NPD;
  float* xconv_r = ws + 2*NPD;
  float* xconv_e = ws + 3*NPD;
  float* dtBC_r  = ws + 4*NPD;
  float* dtBC_e  = ws + 4*NPD + NDBC;
  float* trans_S = ws + 4*NPD + 2*NDBC;                         // NCHAIN*NCHUNK*NS*DIN
  float* sumdt   = trans_S + (size_t)NCHAIN*NCHUNK*NS*DIN;      // NCHAIN*NCHUNK*DIN
  float* hin     = sumdt   + (size_t)NCHAIN*NCHUNK*DIN;         // NCHAIN*NCHUNK*NS*DIN
  float* ym_r = xproj_r;   // xproj dead after conv
  float* ym_e = xproj_e;

  inproj_kernel<<<2*NPOS/PB, DIN, 0, stream>>>(x_rgb, x_e, ipw_r, ipw_e, xproj_r, xproj_e);
  conv_kernel<<<2*NPOS, DIN, 0, stream>>>(xproj_r, xproj_e, cw_r, cb_r, cw_e, cb_e, xconv_r, xconv_e);
  projbc_kernel<<<2*BB*(LL/TPOS), 256, 0, stream>>>(xconv_r, xconv_e, xpw, dtBC_r, dtBC_e);
  scan_p1_kernel<<<NCHAIN*NCHUNK, DIN, 0, stream>>>(xconv_r, xconv_e, dtBC_r, dtBC_e,
                                                    dtw, dtb, Alog, trans_S, sumdt);
  scan_p2_kernel<<<NCHAIN, DIN, 0, stream>>>(trans_S, sumdt, Alog, hin);
  hipMemsetAsync(ym_r, 0, 2*NPD*sizeof(float), stream);  // zero merge accumulators (after conv: xproj dead)
  scan_p3_kernel<<<NCHAIN*NCHUNK, DIN, 0, stream>>>(xconv_r, xconv_e, dtBC_r, dtBC_e,
                                                    dtw, dtb, Alog, Ds_, hin, ym_r, ym_e);
  ln_out_kernel<<<2*NPOS/PB, DIN, 0, stream>>>(ym_r, ym_e, ln_rg, ln_rb, ln_eg, ln_eb,
                                               opw_r, opw_e, x_rgb, x_e, out);
}

// Round 9
// 420.391 us; speedup vs baseline: 9.3996x; 1.1020x over previous
//
#include <hip/hip_runtime.h>

#define BB 4
#define HH 64
#define WW 64
#define CC 96
#define DIN 192
#define NS 4
#define RR 6
#define KK 4
#define LL 4096               // HH*WW
#define NPOS (BB*LL)          // 16384 positions per modality
#define NPD ((size_t)NPOS*DIN)
#define NDBC ((size_t)BB*KK*LL*14)
#define NCHUNK 128
#define CLEN 32               // NCHUNK*CLEN == LL ; CLEN must divide 64
#define NCHAIN 32             // 2 mods * 4 b * 4 k
#define PB 8                  // positions per block in inproj/ln_out

// canonical spatial position for scan-direction k at scan step l
__device__ __forceinline__ int map_pos(int k, int l){
  switch(k){
    case 0: return l;
    case 1: { int wi=l>>6, hi=l&63; return hi*WW+wi; }     // (w,h) flatten -> h*W+w
    case 2: return LL-1-l;
    default:{ int lr=LL-1-l; int wi=lr>>6, hi=lr&63; return hi*WW+wi; }
  }
}
// within a chunk [l0, l0+CLEN) with CLEN | 64, pos is affine: pos = map_pos(k,l0) + i*stride
__device__ __forceinline__ int pos_stride(int k){
  return (k==0) ? 1 : (k==1) ? WW : (k==2) ? -1 : -WW;
}

// ---------------- K1: in_proj (bhwc,dc->bhwd), 8 positions per block -------
__global__ __launch_bounds__(DIN) void inproj_kernel(
    const float* __restrict__ x_rgb, const float* __restrict__ x_e,
    const float* __restrict__ w_r,   const float* __restrict__ w_e,
    float* __restrict__ xproj_r,    float* __restrict__ xproj_e){
  int blk = blockIdx.x;                 // m*(NPOS/PB) + g
  int m = blk / (NPOS/PB); int g = blk % (NPOS/PB);
  size_t rem0 = (size_t)g * PB;
  const float* x = m ? x_e : x_rgb;
  const float* w = m ? w_e : w_r;
  float* o = m ? xproj_e : xproj_r;
  __shared__ float xs[PB][CC];
  __shared__ float wt[DIN][17];         // 16 cols + pad
  int t = threadIdx.x;
  for(int idx=t; idx<PB*CC; idx+=DIN) xs[idx/CC][idx%CC] = x[rem0*CC + idx];
  float acc[PB];
  #pragma unroll
  for(int p=0;p<PB;p++) acc[p]=0.f;
  for(int c0=0; c0<CC; c0+=16){
    __syncthreads();
    for(int idx=t; idx<DIN*16; idx+=DIN){
      int dd = idx>>4, cc = idx&15;
      wt[dd][cc] = w[(size_t)dd*CC + c0 + cc];
    }
    __syncthreads();
    #pragma unroll
    for(int cc=0; cc<16; cc++){
      float wv = wt[t][cc];
      #pragma unroll
      for(int p=0;p<PB;p++) acc[p] += xs[p][c0+cc]*wv;
    }
  }
  #pragma unroll
  for(int p=0;p<PB;p++) o[(rem0+p)*DIN + t] = acc[p];
}

// ---------------- K2: depthwise 3x3 conv (SAME, zero pad) + bias + SiLU ----
__global__ __launch_bounds__(DIN) void conv_kernel(
    const float* __restrict__ xproj_r, const float* __restrict__ xproj_e,
    const float* __restrict__ cw_r, const float* __restrict__ cb_r,
    const float* __restrict__ cw_e, const float* __restrict__ cb_e,
    float* __restrict__ xconv_r, float* __restrict__ xconv_e){
  int blk = blockIdx.x;
  int m = blk / NPOS; int rem = blk % NPOS;
  int b = rem / LL, p = rem % LL;
  int y = p >> 6, x = p & 63;           // p = y*WW + x
  const float* in = (m ? xproj_e : xproj_r) + (size_t)b*LL*DIN;
  const float* cw = m ? cw_e : cw_r;
  const float* cb = m ? cb_e : cb_r;
  float* out = m ? xconv_e : xconv_r;
  int d = threadIdx.x;
  float acc = cb[d];
  #pragma unroll
  for(int dy=-1;dy<=1;dy++){
    int yy = y+dy; if(yy<0 || yy>=HH) continue;
    #pragma unroll
    for(int dx=-1;dx<=1;dx++){
      int xx = x+dx; if(xx<0 || xx>=WW) continue;
      acc += in[(size_t)(yy*WW+xx)*DIN + d] * cw[d*9 + (dy+1)*3 + (dx+1)];
    }
  }
  float s = acc / (1.f + __expf(-acc));  // silu
  out[(size_t)(b*LL+p)*DIN + d] = s;
}

// -------- K3: x_proj as LDS-tiled mini-GEMM over canonical positions -------
#define TPOS 32               // positions per block
__global__ __launch_bounds__(256) void projbc_kernel(
    const float* __restrict__ xconv_r, const float* __restrict__ xconv_e,
    const float* __restrict__ xpw,
    float* __restrict__ dtBC_r, float* __restrict__ dtBC_e){
  int blk = blockIdx.x;                 // m*(BB*LL/TPOS) + b*(LL/TPOS) + tile
  int m = blk / (BB*LL/TPOS); int rem = blk % (BB*LL/TPOS);
  int b = rem / (LL/TPOS); int p0 = (rem % (LL/TPOS)) * TPOS;
  const float* xc = (m ? xconv_e : xconv_r) + ((size_t)b*LL + p0)*DIN;
  float* o = (m ? dtBC_e : dtBC_r) + (size_t)b*KK*LL*14;

  // stride-97 rows: 97%32==1 -> bank(p*97+d)=(p+d)%32, conflict-free
  __shared__ float xs[TPOS*97];         // 32 pos x 96 d-tile
  __shared__ float wsd[56*97];          // 56 cbar x 96 d-tile

  int t = threadIdx.x;
  int g = t >> 5;                       // 0..7 : handles cbar = g*7 .. g*7+6
  int pl = t & 31;                      // position within tile

  float acc[7];
  #pragma unroll
  for(int j=0;j<7;j++) acc[j]=0.f;

  for(int dt0=0; dt0<DIN; dt0+=96){
    __syncthreads();
    for(int idx=t; idx<TPOS*96; idx+=256){
      int r = idx/96, ccol = idx%96;
      xs[r*97+ccol] = xc[(size_t)r*DIN + dt0 + ccol];
    }
    for(int idx=t; idx<56*96; idx+=256){
      int r = idx/96, ccol = idx%96;
      wsd[r*97+ccol] = xpw[(size_t)r*DIN + dt0 + ccol];
    }
    __syncthreads();
    const float* xrow = &xs[pl*97];
    #pragma unroll 4
    for(int d=0; d<96; d++){
      float xv = xrow[d];
      #pragma unroll
      for(int j=0;j<7;j++) acc[j] += wsd[(g*7+j)*97 + d]*xv;
    }
  }

  int p = p0 + pl;
  int ptr_ = (p&63)*64 + (p>>6);        // inverse of the transpose map
  #pragma unroll
  for(int j=0;j<7;j++){
    int cbar = g*7+j;
    int k = cbar/14, c = cbar%14;
    int l = (k==0) ? p : (k==1) ? ptr_ : (k==2) ? (LL-1-p) : (LL-1-ptr_);
    o[((size_t)k*LL + l)*14 + c] = acc[j];
  }
}

// db4 row layout (16 floats): [0-3]=B, [4-7]=C(p3 only), [8-13]=dtl, [14-15]=pad
// ------- K4a: per-chunk local scan -> (end state S, sum of dt) -------------
__global__ __launch_bounds__(DIN) void scan_p1_kernel(
    const float* __restrict__ xconv_r, const float* __restrict__ xconv_e,
    const float* __restrict__ dtBC_r, const float* __restrict__ dtBC_e,
    const float* __restrict__ dtw, const float* __restrict__ dtb,
    const float* __restrict__ A_logs,
    float* __restrict__ trans_S, float* __restrict__ sumdt){
  int ch = blockIdx.x / NCHUNK;         // m*16 + b*4 + k
  int cidx = blockIdx.x % NCHUNK;
  int m = ch >> 4, b = (ch>>2)&3, k = ch&3;
  int d = threadIdx.x;
  int l0 = cidx*CLEN;

  float4 al = *(const float4*)&A_logs[(size_t)(k*DIN+d)*NS];
  float A0=-__expf(al.x), A1=-__expf(al.y), A2=-__expf(al.z), A3=-__expf(al.w);
  float Wd[RR];
  #pragma unroll
  for(int r=0;r<RR;r++) Wd[r] = dtw[((size_t)k*DIN + d)*RR + r];
  float bias = dtb[k*DIN+d];

  const float* xc    = (m ? xconv_e : xconv_r) + (size_t)b*LL*DIN;
  const float* dbc_m = (m ? dtBC_e : dtBC_r) + ((size_t)b*KK + k)*LL*14;

  __shared__ float4 db4[CLEN][4];
  __shared__ float u_s[CLEN*DIN];
  float* dbf = (float*)db4;

  for(int idx=d; idx<CLEN*14; idx+=DIN){
    int i = idx/14, j = idx%14;
    int slot = (j<6) ? (8+j) : (j-6);
    dbf[i*16+slot] = dbc_m[(size_t)l0*14 + idx];
  }
  int stride = pos_stride(k);
  int pos0 = map_pos(k, l0);
  #pragma unroll 8
  for(int i=0;i<CLEN;i++)
    u_s[i*DIN+d] = xc[(size_t)(pos0+i*stride)*DIN + d];
  __syncthreads();

  float h0=0.f,h1=0.f,h2=0.f,h3=0.f,sd=0.f;
  #pragma unroll 4
  for(int i=0;i<CLEN;i++){
    float4 Bv  = db4[i][0];
    float4 d03 = db4[i][2];
    float4 d45 = db4[i][3];
    float dtr = fmaf(d03.x,Wd[0], fmaf(d03.y,Wd[1], fmaf(d03.z,Wd[2],
                fmaf(d03.w,Wd[3], fmaf(d45.x,Wd[4], fmaf(d45.y,Wd[5], bias))))));
    float dt = fmaxf(dtr,0.f) + __logf(1.f + __expf(-fabsf(dtr)));
    sd += dt;
    float u = u_s[i*DIN + d];
    float dtu = dt*u;
    h0 = fmaf(h0, __expf(dt*A0), dtu*Bv.x);
    h1 = fmaf(h1, __expf(dt*A1), dtu*Bv.y);
    h2 = fmaf(h2, __expf(dt*A2), dtu*Bv.z);
    h3 = fmaf(h3, __expf(dt*A3), dtu*Bv.w);
  }
  size_t base = ((size_t)(ch*NCHUNK + cidx)*NS)*DIN + d;
  trans_S[base          ] = h0;
  trans_S[base +   DIN  ] = h1;
  trans_S[base + 2*DIN  ] = h2;
  trans_S[base + 3*DIN  ] = h3;
  sumdt[(size_t)(ch*NCHUNK + cidx)*DIN + d] = sd;
}

// ------- K4b: sequential inter-chunk scan -> entering state per chunk ------
__global__ __launch_bounds__(DIN) void scan_p2_kernel(
    const float* __restrict__ trans_S, const float* __restrict__ sumdt,
    const float* __restrict__ A_logs, float* __restrict__ hin){
  int ch = blockIdx.x; int k = ch & 3; int d = threadIdx.x;
  float4 al = *(const float4*)&A_logs[(size_t)(k*DIN+d)*NS];
  float A[NS] = {-__expf(al.x), -__expf(al.y), -__expf(al.z), -__expf(al.w)};
  float h[NS] = {0.f,0.f,0.f,0.f};
  for(int c0=0;c0<NCHUNK;c0+=4){
    float S[4][NS], sdv[4];
    #pragma unroll
    for(int cc=0;cc<4;cc++){
      size_t base = ((size_t)(ch*NCHUNK + c0+cc)*NS)*DIN + d;
      #pragma unroll
      for(int n=0;n<NS;n++) S[cc][n] = trans_S[base + (size_t)n*DIN];
      sdv[cc] = sumdt[(size_t)(ch*NCHUNK + c0+cc)*DIN + d];
    }
    #pragma unroll
    for(int cc=0;cc<4;cc++){
      size_t base = ((size_t)(ch*NCHUNK + c0+cc)*NS)*DIN + d;
      #pragma unroll
      for(int n=0;n<NS;n++) hin[base + (size_t)n*DIN] = h[n];
      #pragma unroll
      for(int n=0;n<NS;n++) h[n] = fmaf(h[n], __expf(A[n]*sdv[cc]), S[cc][n]);
    }
  }
}

// ------- K4c: paired-direction chunk scan, atomic-free merge ---------------
// Pair (kA, kB=kA+2) traverse the SAME position segment in opposite order.
// Loop A writes ym[pos] = yA; loop B does ym[pos] += yB (same thread+addr,
// program-order safe). pg=0 pairs k{0,2} -> ym_a; pg=1 pairs k{1,3} -> ym_b.
// ln_out sums ym_a + ym_b. No atomics, no memset.
__global__ __launch_bounds__(DIN) void scan_p3_kernel(
    const float* __restrict__ xconv_r, const float* __restrict__ xconv_e,
    const float* __restrict__ dtBC_r, const float* __restrict__ dtBC_e,
    const float* __restrict__ dtw, const float* __restrict__ dtb,
    const float* __restrict__ A_logs, const float* __restrict__ Ds,
    const float* __restrict__ hin,
    float* __restrict__ ym_a_r, float* __restrict__ ym_a_e,
    float* __restrict__ ym_b_r, float* __restrict__ ym_b_e){
  int blk = blockIdx.x;                 // ((m*4+b)*2+pg)*NCHUNK + cidx
  int cidx = blk % NCHUNK;
  int rem  = blk / NCHUNK;
  int pg = rem & 1; rem >>= 1;
  int b  = rem & 3; int m = rem >> 2;
  int kA = pg, kB = pg + 2;             // paired directions
  int cidx2 = NCHUNK-1-cidx;            // B-chain chunk covering same segment
  int l0A = cidx*CLEN, l0B = cidx2*CLEN;

  int d = threadIdx.x;
  int st = pos_stride(kA);
  int pos0 = map_pos(kA, l0A);

  const float* xc = (m ? xconv_e : xconv_r) + (size_t)b*LL*DIN;
  const float* dbc_own = (m ? dtBC_e : dtBC_r) + (size_t)b*KK*LL*14;
  const float* dbc_oth = (m ? dtBC_r : dtBC_e) + (size_t)b*KK*LL*14;
  float* ym = (pg==0) ? (m ? ym_a_e : ym_a_r) : (m ? ym_b_e : ym_b_r);
  ym += (size_t)b*LL*DIN;

  __shared__ float4 db4A[CLEN][4];
  __shared__ float4 db4B[CLEN][4];
  __shared__ float u_s[CLEN*DIN];
  float* dbfA = (float*)db4A;
  float* dbfB = (float*)db4B;

  // stage dt/B (own) + C (other) for both chains
  for(int idx=d; idx<CLEN*14; idx+=DIN){
    int i = idx/14, j = idx%14;
    int slot = (j<6) ? (8+j) : (j-6);
    dbfA[i*16+slot] = dbc_own[((size_t)kA*LL + l0A)*14 + idx];
    dbfB[i*16+slot] = dbc_own[((size_t)kB*LL + l0B)*14 + idx];
  }
  for(int idx=d; idx<CLEN*NS; idx+=DIN){
    int i = idx>>2, j = idx&3;
    dbfA[i*16 + 4 + j] = dbc_oth[((size_t)kA*LL + l0A + i)*14 + 10 + j];
    dbfB[i*16 + 4 + j] = dbc_oth[((size_t)kB*LL + l0B + i)*14 + 10 + j];
  }
  #pragma unroll 8
  for(int i=0;i<CLEN;i++)
    u_s[i*DIN+d] = xc[(size_t)(pos0+i*st)*DIN + d];
  __syncthreads();

  // ---------- loop A: direction kA, forward over segment ----------
  {
    int k = kA;
    float4 al = *(const float4*)&A_logs[(size_t)(k*DIN+d)*NS];
    float A0=-__expf(al.x), A1=-__expf(al.y), A2=-__expf(al.z), A3=-__expf(al.w);
    float Wd[RR];
    #pragma unroll
    for(int r=0;r<RR;r++) Wd[r] = dtw[((size_t)k*DIN + d)*RR + r];
    float bias = dtb[k*DIN+d];
    float Dv = Ds[k*DIN+d];
    int chA = (m*4+b)*4 + kA;  // == m*16+b*4+kA
    size_t hbase = ((size_t)(chA*NCHUNK + cidx)*NS)*DIN + d;
    float h0=hin[hbase], h1=hin[hbase+DIN], h2=hin[hbase+2*DIN], h3=hin[hbase+3*DIN];
    #pragma unroll 4
    for(int i=0;i<CLEN;i++){
      float4 Bv  = db4A[i][0];
      float4 Cv  = db4A[i][1];
      float4 d03 = db4A[i][2];
      float4 d45 = db4A[i][3];
      float dtr = fmaf(d03.x,Wd[0], fmaf(d03.y,Wd[1], fmaf(d03.z,Wd[2],
                  fmaf(d03.w,Wd[3], fmaf(d45.x,Wd[4], fmaf(d45.y,Wd[5], bias))))));
      float dt = fmaxf(dtr,0.f) + __logf(1.f + __expf(-fabsf(dtr)));
      float u = u_s[i*DIN + d];
      float dtu = dt*u;
      h0 = fmaf(h0, __expf(dt*A0), dtu*Bv.x);
      h1 = fmaf(h1, __expf(dt*A1), dtu*Bv.y);
      h2 = fmaf(h2, __expf(dt*A2), dtu*Bv.z);
      h3 = fmaf(h3, __expf(dt*A3), dtu*Bv.w);
      float y = fmaf(h0,Cv.x, fmaf(h1,Cv.y, fmaf(h2,Cv.z, fmaf(h3,Cv.w, Dv*u))));
      ym[(size_t)(pos0+i*st)*DIN + d] = y;
    }
  }
  // ---------- loop B: direction kB, same segment reversed ----------
  {
    int k = kB;
    float4 al = *(const float4*)&A_logs[(size_t)(k*DIN+d)*NS];
    float A0=-__expf(al.x), A1=-__expf(al.y), A2=-__expf(al.z), A3=-__expf(al.w);
    float Wd[RR];
    #pragma unroll
    for(int r=0;r<RR;r++) Wd[r] = dtw[((size_t)k*DIN + d)*RR + r];
    float bias = dtb[k*DIN+d];
    float Dv = Ds[k*DIN+d];
    int chB = (m*4+b)*4 + kB;
    size_t hbase = ((size_t)(chB*NCHUNK + cidx2)*NS)*DIN + d;
    float h0=hin[hbase], h1=hin[hbase+DIN], h2=hin[hbase+2*DIN], h3=hin[hbase+3*DIN];
    #pragma unroll 4
    for(int j=0;j<CLEN;j++){
      int pi = CLEN-1-j;               // position index within segment
      float4 Bv  = db4B[j][0];
      float4 Cv  = db4B[j][1];
      float4 d03 = db4B[j][2];
      float4 d45 = db4B[j][3];
      float dtr = fmaf(d03.x,Wd[0], fmaf(d03.y,Wd[1], fmaf(d03.z,Wd[2],
                  fmaf(d03.w,Wd[3], fmaf(d45.x,Wd[4], fmaf(d45.y,Wd[5], bias))))));
      float dt = fmaxf(dtr,0.f) + __logf(1.f + __expf(-fabsf(dtr)));
      float u = u_s[pi*DIN + d];
      float dtu = dt*u;
      h0 = fmaf(h0, __expf(dt*A0), dtu*Bv.x);
      h1 = fmaf(h1, __expf(dt*A1), dtu*Bv.y);
      h2 = fmaf(h2, __expf(dt*A2), dtu*Bv.z);
      h3 = fmaf(h3, __expf(dt*A3), dtu*Bv.w);
      float y = fmaf(h0,Cv.x, fmaf(h1,Cv.y, fmaf(h2,Cv.z, fmaf(h3,Cv.w, Dv*u))));
      size_t a = (size_t)(pos0+pi*st)*DIN + d;
      ym[a] += y;                      // same thread wrote ym[a] in loop A
    }
  }
}

// ------- K5: LayerNorm(192) over (ym_a+ym_b) + out_proj + residual ---------
__global__ __launch_bounds__(DIN) void ln_out_kernel(
    const float* __restrict__ ym_a_r, const float* __restrict__ ym_a_e,
    const float* __restrict__ ym_b_r, const float* __restrict__ ym_b_e,
    const float* __restrict__ ln_rg, const float* __restrict__ ln_rb,
    const float* __restrict__ ln_eg, const float* __restrict__ ln_eb,
    const float* __restrict__ opw_r, const float* __restrict__ opw_e,
    const float* __restrict__ x_rgb, const float* __restrict__ x_e,
    float* __restrict__ out){
  int blk = blockIdx.x;                 // m*(NPOS/PB) + g
  int m = blk / (NPOS/PB); int g = blk % (NPOS/PB);
  size_t rem0 = (size_t)g * PB;
  const float* yma = (m ? ym_a_e : ym_a_r) + rem0*DIN;
  const float* ymb = (m ? ym_b_e : ym_b_r) + rem0*DIN;
  int t = threadIdx.x;
  int wid = t>>6;

  float v[PB];
  #pragma unroll
  for(int p=0;p<PB;p++) v[p] = yma[(size_t)p*DIN + t] + ymb[(size_t)p*DIN + t];

  __shared__ float red_s[PB][3], red_q[PB][3];
  #pragma unroll
  for(int p=0;p<PB;p++){
    float s = v[p], q = v[p]*v[p];
    #pragma unroll
    for(int off=32; off>0; off>>=1){ s += __shfl_down(s,off); q += __shfl_down(q,off); }
    if((t&63)==0){ red_s[p][wid]=s; red_q[p][wid]=q; }
  }
  __syncthreads();

  const float* gg = m ? ln_eg : ln_rg;
  const float* be = m ? ln_eb : ln_rb;
  __shared__ float yn_s[PB][DIN];
  float gv = gg[t], bv = be[t];
  #pragma unroll
  for(int p=0;p<PB;p++){
    float S = red_s[p][0]+red_s[p][1]+red_s[p][2];
    float Q = red_q[p][0]+red_q[p][1]+red_q[p][2];
    float mu  = S*(1.f/DIN);
    float var = Q*(1.f/DIN) - mu*mu;
    float inv = rsqrtf(var + 1e-5f);
    yn_s[p][t] = (v[p]-mu)*inv*gv + bv;
  }
  __syncthreads();

  // out-proj: thread t -> c = t%96, positions {t/96, t/96+2, t/96+4, t/96+6}
  int c = t % CC;
  int pbase = t / CC;                    // 0 or 1
  const float* w = (m ? opw_e : opw_r) + (size_t)c*DIN;
  float acc[4] = {0.f,0.f,0.f,0.f};
  for(int dd=0; dd<DIN; dd++){
    float wv = w[dd];
    #pragma unroll
    for(int pp=0;pp<4;pp++) acc[pp] += yn_s[pbase + 2*pp][dd]*wv;
  }
  const float* xin = m ? x_e : x_rgb;
  #pragma unroll
  for(int pp=0;pp<4;pp++){
    size_t rem = rem0 + pbase + 2*pp;
    size_t oi = (size_t)m*NPOS*CC + rem*CC + c;
    out[oi] = acc[pp] + xin[rem*CC + c];
  }
}

extern "C" void kernel_launch(void* const* d_in, const int* in_sizes, int n_in,
                              void* d_out, int out_size, void* d_ws, size_t ws_size,
                              hipStream_t stream){
  const float* x_rgb = (const float*)d_in[0];
  const float* x_e   = (const float*)d_in[1];
  const float* ipw_r = (const float*)d_in[2];
  const float* ipw_e = (const float*)d_in[3];
  const float* cw_r  = (const float*)d_in[4];
  const float* cb_r  = (const float*)d_in[5];
  const float* cw_e  = (const float*)d_in[6];
  const float* cb_e  = (const float*)d_in[7];
  const float* xpw   = (const float*)d_in[8];
  const float* dtw   = (const float*)d_in[9];
  const float* dtb   = (const float*)d_in[10];
  const float* Alog  = (const float*)d_in[11];
  const float* Ds_   = (const float*)d_in[12];
  const float* ln_rg = (const float*)d_in[13];
  const float* ln_rb = (const float*)d_in[14];
  const float* ln_eg = (const float*)d_in[15];
  const float* ln_eb = (const float*)d_in[16];
  const float* opw_r = (const float*)d_in[17];
  const float* opw_e = (const float*)d_in[18];
  float* out = (float*)d_out;

  float* ws = (float*)d_ws;
  float* xproj_r = ws;
  float* xproj_e = ws + NPD;
  float* xconv_r = ws + 2*NPD;
  float* xconv_e = ws + 3*NPD;
  float* dtBC_r  = ws + 4*NPD;
  float* dtBC_e  = ws + 4*NPD + NDBC;
  float* trans_S = ws + 4*NPD + 2*NDBC;                         // NCHAIN*NCHUNK*NS*DIN
  float* sumdt   = trans_S + (size_t)NCHAIN*NCHUNK*NS*DIN;      // NCHAIN*NCHUNK*DIN
  float* hin     = sumdt   + (size_t)NCHAIN*NCHUNK*DIN;         // NCHAIN*NCHUNK*NS*DIN
  float* ym_b_r  = hin     + (size_t)NCHAIN*NCHUNK*NS*DIN;      // NPD
  float* ym_b_e  = ym_b_r + NPD;                                // NPD
  float* ym_a_r = xproj_r;   // xproj dead after conv
  float* ym_a_e = xproj_e;

  inproj_kernel<<<2*NPOS/PB, DIN, 0, stream>>>(x_rgb, x_e, ipw_r, ipw_e, xproj_r, xproj_e);
  conv_kernel<<<2*NPOS, DIN, 0, stream>>>(xproj_r, xproj_e, cw_r, cb_r, cw_e, cb_e, xconv_r, xconv_e);
  projbc_kernel<<<2*BB*(LL/TPOS), 256, 0, stream>>>(xconv_r, xconv_e, xpw, dtBC_r, dtBC_e);
  scan_p1_kernel<<<NCHAIN*NCHUNK, DIN, 0, stream>>>(xconv_r, xconv_e, dtBC_r, dtBC_e,
                                                    dtw, dtb, Alog, trans_S, sumdt);
  scan_p2_kernel<<<NCHAIN, DIN, 0, stream>>>(trans_S, sumdt, Alog, hin);
  scan_p3_kernel<<<2*BB*2*NCHUNK, DIN, 0, stream>>>(xconv_r, xconv_e, dtBC_r, dtBC_e,
                                                    dtw, dtb, Alog, Ds_, hin,
                                                    ym_a_r, ym_a_e, ym_b_r, ym_b_e);
  ln_out_kernel<<<2*NPOS/PB, DIN, 0, stream>>>(ym_a_r, ym_a_e, ym_b_r, ym_b_e,
                                               ln_rg, ln_rb, ln_eg, ln_eb,
                                               opw_r, opw_e, x_rgb, x_e, out);
}

// Round 10
// 411.417 us; speedup vs baseline: 9.6046x; 1.0218x over previous
//
#include <hip/hip_runtime.h>

#define BB 4
#define HH 64
#define WW 64
#define CC 96
#define DIN 192
#define NS 4
#define RR 6
#define KK 4
#define LL 4096               // HH*WW
#define NPOS (BB*LL)          // 16384 positions per modality
#define NPD ((size_t)NPOS*DIN)
#define NDBC ((size_t)BB*KK*LL*14)
#define NCHUNK 128
#define CLEN 32               // NCHUNK*CLEN == LL ; CLEN must divide 64
#define NCHAIN 32             // 2 mods * 4 b * 4 k
#define PB 8                  // positions per block in inproj/ln_out

// canonical spatial position for scan-direction k at scan step l
__device__ __forceinline__ int map_pos(int k, int l){
  switch(k){
    case 0: return l;
    case 1: { int wi=l>>6, hi=l&63; return hi*WW+wi; }     // (w,h) flatten -> h*W+w
    case 2: return LL-1-l;
    default:{ int lr=LL-1-l; int wi=lr>>6, hi=lr&63; return hi*WW+wi; }
  }
}
// within a chunk [l0, l0+CLEN) with CLEN | 64, pos is affine: pos = map_pos(k,l0) + i*stride
__device__ __forceinline__ int pos_stride(int k){
  return (k==0) ? 1 : (k==1) ? WW : (k==2) ? -1 : -WW;
}

// ---------------- K1: in_proj (bhwc,dc->bhwd), 8 positions per block -------
__global__ __launch_bounds__(DIN) void inproj_kernel(
    const float* __restrict__ x_rgb, const float* __restrict__ x_e,
    const float* __restrict__ w_r,   const float* __restrict__ w_e,
    float* __restrict__ xproj_r,    float* __restrict__ xproj_e){
  int blk = blockIdx.x;                 // m*(NPOS/PB) + g
  int m = blk / (NPOS/PB); int g = blk % (NPOS/PB);
  size_t rem0 = (size_t)g * PB;
  const float* x = m ? x_e : x_rgb;
  const float* w = m ? w_e : w_r;
  float* o = m ? xproj_e : xproj_r;
  __shared__ float xs[PB][CC];
  __shared__ float wt[DIN][17];         // 16 cols + pad
  int t = threadIdx.x;
  for(int idx=t; idx<PB*CC; idx+=DIN) xs[idx/CC][idx%CC] = x[rem0*CC + idx];
  float acc[PB];
  #pragma unroll
  for(int p=0;p<PB;p++) acc[p]=0.f;
  for(int c0=0; c0<CC; c0+=16){
    __syncthreads();
    for(int idx=t; idx<DIN*16; idx+=DIN){
      int dd = idx>>4, cc = idx&15;
      wt[dd][cc] = w[(size_t)dd*CC + c0 + cc];
    }
    __syncthreads();
    #pragma unroll
    for(int cc=0; cc<16; cc++){
      float wv = wt[t][cc];
      #pragma unroll
      for(int p=0;p<PB;p++) acc[p] += xs[p][c0+cc]*wv;
    }
  }
  #pragma unroll
  for(int p=0;p<PB;p++) o[(rem0+p)*DIN + t] = acc[p];
}

// ---------------- K2: depthwise 3x3 conv (SAME, zero pad) + bias + SiLU ----
__global__ __launch_bounds__(DIN) void conv_kernel(
    const float* __restrict__ xproj_r, const float* __restrict__ xproj_e,
    const float* __restrict__ cw_r, const float* __restrict__ cb_r,
    const float* __restrict__ cw_e, const float* __restrict__ cb_e,
    float* __restrict__ xconv_r, float* __restrict__ xconv_e){
  int blk = blockIdx.x;
  int m = blk / NPOS; int rem = blk % NPOS;
  int b = rem / LL, p = rem % LL;
  int y = p >> 6, x = p & 63;           // p = y*WW + x
  const float* in = (m ? xproj_e : xproj_r) + (size_t)b*LL*DIN;
  const float* cw = m ? cw_e : cw_r;
  const float* cb = m ? cb_e : cb_r;
  float* out = m ? xconv_e : xconv_r;
  int d = threadIdx.x;
  float acc = cb[d];
  #pragma unroll
  for(int dy=-1;dy<=1;dy++){
    int yy = y+dy; if(yy<0 || yy>=HH) continue;
    #pragma unroll
    for(int dx=-1;dx<=1;dx++){
      int xx = x+dx; if(xx<0 || xx>=WW) continue;
      acc += in[(size_t)(yy*WW+xx)*DIN + d] * cw[d*9 + (dy+1)*3 + (dx+1)];
    }
  }
  float s = acc / (1.f + __expf(-acc));  // silu
  out[(size_t)(b*LL+p)*DIN + d] = s;
}

// -------- K3: x_proj as LDS-tiled mini-GEMM over canonical positions -------
#define TPOS 32               // positions per block
__global__ __launch_bounds__(256) void projbc_kernel(
    const float* __restrict__ xconv_r, const float* __restrict__ xconv_e,
    const float* __restrict__ xpw,
    float* __restrict__ dtBC_r, float* __restrict__ dtBC_e){
  int blk = blockIdx.x;                 // m*(BB*LL/TPOS) + b*(LL/TPOS) + tile
  int m = blk / (BB*LL/TPOS); int rem = blk % (BB*LL/TPOS);
  int b = rem / (LL/TPOS); int p0 = (rem % (LL/TPOS)) * TPOS;
  const float* xc = (m ? xconv_e : xconv_r) + ((size_t)b*LL + p0)*DIN;
  float* o = (m ? dtBC_e : dtBC_r) + (size_t)b*KK*LL*14;

  // stride-97 rows: 97%32==1 -> bank(p*97+d)=(p+d)%32, conflict-free
  __shared__ float xs[TPOS*97];         // 32 pos x 96 d-tile
  __shared__ float wsd[56*97];          // 56 cbar x 96 d-tile

  int t = threadIdx.x;
  int g = t >> 5;                       // 0..7 : handles cbar = g*7 .. g*7+6
  int pl = t & 31;                      // position within tile

  float acc[7];
  #pragma unroll
  for(int j=0;j<7;j++) acc[j]=0.f;

  for(int dt0=0; dt0<DIN; dt0+=96){
    __syncthreads();
    for(int idx=t; idx<TPOS*96; idx+=256){
      int r = idx/96, ccol = idx%96;
      xs[r*97+ccol] = xc[(size_t)r*DIN + dt0 + ccol];
    }
    for(int idx=t; idx<56*96; idx+=256){
      int r = idx/96, ccol = idx%96;
      wsd[r*97+ccol] = xpw[(size_t)r*DIN + dt0 + ccol];
    }
    __syncthreads();
    const float* xrow = &xs[pl*97];
    #pragma unroll 4
    for(int d=0; d<96; d++){
      float xv = xrow[d];
      #pragma unroll
      for(int j=0;j<7;j++) acc[j] += wsd[(g*7+j)*97 + d]*xv;
    }
  }

  int p = p0 + pl;
  int ptr_ = (p&63)*64 + (p>>6);        // inverse of the transpose map
  #pragma unroll
  for(int j=0;j<7;j++){
    int cbar = g*7+j;
    int k = cbar/14, c = cbar%14;
    int l = (k==0) ? p : (k==1) ? ptr_ : (k==2) ? (LL-1-p) : (LL-1-ptr_);
    o[((size_t)k*LL + l)*14 + c] = acc[j];
  }
}

// db4 row layout (16 floats): [0-3]=B, [4-7]=C(p3 only), [8-13]=dtl, [14-15]=pad
// ------- K4a: per-chunk local scan -> (end state S, sum of dt) -------------
__global__ __launch_bounds__(DIN) void scan_p1_kernel(
    const float* __restrict__ xconv_r, const float* __restrict__ xconv_e,
    const float* __restrict__ dtBC_r, const float* __restrict__ dtBC_e,
    const float* __restrict__ dtw, const float* __restrict__ dtb,
    const float* __restrict__ A_logs,
    float* __restrict__ trans_S, float* __restrict__ sumdt){
  int ch = blockIdx.x / NCHUNK;         // m*16 + b*4 + k
  int cidx = blockIdx.x % NCHUNK;
  int m = ch >> 4, b = (ch>>2)&3, k = ch&3;
  int d = threadIdx.x;
  int l0 = cidx*CLEN;

  float4 al = *(const float4*)&A_logs[(size_t)(k*DIN+d)*NS];
  float A0=-__expf(al.x), A1=-__expf(al.y), A2=-__expf(al.z), A3=-__expf(al.w);
  float Wd[RR];
  #pragma unroll
  for(int r=0;r<RR;r++) Wd[r] = dtw[((size_t)k*DIN + d)*RR + r];
  float bias = dtb[k*DIN+d];

  const float* xc    = (m ? xconv_e : xconv_r) + (size_t)b*LL*DIN;
  const float* dbc_m = (m ? dtBC_e : dtBC_r) + ((size_t)b*KK + k)*LL*14;

  __shared__ float4 db4[CLEN][4];
  __shared__ float u_s[CLEN*DIN];
  float* dbf = (float*)db4;

  for(int idx=d; idx<CLEN*14; idx+=DIN){
    int i = idx/14, j = idx%14;
    int slot = (j<6) ? (8+j) : (j-6);
    dbf[i*16+slot] = dbc_m[(size_t)l0*14 + idx];
  }
  int stride = pos_stride(k);
  int pos0 = map_pos(k, l0);
  #pragma unroll 8
  for(int i=0;i<CLEN;i++)
    u_s[i*DIN+d] = xc[(size_t)(pos0+i*stride)*DIN + d];
  __syncthreads();

  float h0=0.f,h1=0.f,h2=0.f,h3=0.f,sd=0.f;
  #pragma unroll 4
  for(int i=0;i<CLEN;i++){
    float4 Bv  = db4[i][0];
    float4 d03 = db4[i][2];
    float4 d45 = db4[i][3];
    float dtr = fmaf(d03.x,Wd[0], fmaf(d03.y,Wd[1], fmaf(d03.z,Wd[2],
                fmaf(d03.w,Wd[3], fmaf(d45.x,Wd[4], fmaf(d45.y,Wd[5], bias))))));
    float dt = fmaxf(dtr,0.f) + __logf(1.f + __expf(-fabsf(dtr)));
    sd += dt;
    float u = u_s[i*DIN + d];
    float dtu = dt*u;
    h0 = fmaf(h0, __expf(dt*A0), dtu*Bv.x);
    h1 = fmaf(h1, __expf(dt*A1), dtu*Bv.y);
    h2 = fmaf(h2, __expf(dt*A2), dtu*Bv.z);
    h3 = fmaf(h3, __expf(dt*A3), dtu*Bv.w);
  }
  size_t base = ((size_t)(ch*NCHUNK + cidx)*NS)*DIN + d;
  trans_S[base          ] = h0;
  trans_S[base +   DIN  ] = h1;
  trans_S[base + 2*DIN  ] = h2;
  trans_S[base + 3*DIN  ] = h3;
  sumdt[(size_t)(ch*NCHUNK + cidx)*DIN + d] = sd;
}

// ------- K4b: sequential inter-chunk scan -> entering state per chunk ------
__global__ __launch_bounds__(DIN) void scan_p2_kernel(
    const float* __restrict__ trans_S, const float* __restrict__ sumdt,
    const float* __restrict__ A_logs, float* __restrict__ hin){
  int ch = blockIdx.x; int k = ch & 3; int d = threadIdx.x;
  float4 al = *(const float4*)&A_logs[(size_t)(k*DIN+d)*NS];
  float A[NS] = {-__expf(al.x), -__expf(al.y), -__expf(al.z), -__expf(al.w)};
  float h[NS] = {0.f,0.f,0.f,0.f};
  for(int c0=0;c0<NCHUNK;c0+=4){
    float S[4][NS], sdv[4];
    #pragma unroll
    for(int cc=0;cc<4;cc++){
      size_t base = ((size_t)(ch*NCHUNK + c0+cc)*NS)*DIN + d;
      #pragma unroll
      for(int n=0;n<NS;n++) S[cc][n] = trans_S[base + (size_t)n*DIN];
      sdv[cc] = sumdt[(size_t)(ch*NCHUNK + c0+cc)*DIN + d];
    }
    #pragma unroll
    for(int cc=0;cc<4;cc++){
      size_t base = ((size_t)(ch*NCHUNK + c0+cc)*NS)*DIN + d;
      #pragma unroll
      for(int n=0;n<NS;n++) hin[base + (size_t)n*DIN] = h[n];
      #pragma unroll
      for(int n=0;n<NS;n++) h[n] = fmaf(h[n], __expf(A[n]*sdv[cc]), S[cc][n]);
    }
  }
}

// ------- K4c: paired-direction chunk scan, atomic-free merge ---------------
// Pair (kA, kB=kA+2) traverse the SAME position segment in opposite order.
// Loop A writes ym[pos] = yA; loop B does ym[pos] += yB (same thread+addr,
// program-order safe). pg=0 pairs k{0,2} -> ym_a; pg=1 pairs k{1,3} -> ym_b.
// ln_out sums ym_a + ym_b. No atomics, no memset.
__global__ __launch_bounds__(DIN) void scan_p3_kernel(
    const float* __restrict__ xconv_r, const float* __restrict__ xconv_e,
    const float* __restrict__ dtBC_r, const float* __restrict__ dtBC_e,
    const float* __restrict__ dtw, const float* __restrict__ dtb,
    const float* __restrict__ A_logs, const float* __restrict__ Ds,
    const float* __restrict__ hin,
    float* __restrict__ ym_a_r, float* __restrict__ ym_a_e,
    float* __restrict__ ym_b_r, float* __restrict__ ym_b_e){
  int blk = blockIdx.x;                 // ((m*4+b)*2+pg)*NCHUNK + cidx
  int cidx = blk % NCHUNK;
  int rem  = blk / NCHUNK;
  int pg = rem & 1; rem >>= 1;
  int b  = rem & 3; int m = rem >> 2;
  int kA = pg, kB = pg + 2;             // paired directions
  int cidx2 = NCHUNK-1-cidx;            // B-chain chunk covering same segment
  int l0A = cidx*CLEN, l0B = cidx2*CLEN;

  int d = threadIdx.x;
  int st = pos_stride(kA);
  int pos0 = map_pos(kA, l0A);

  const float* xc = (m ? xconv_e : xconv_r) + (size_t)b*LL*DIN;
  const float* dbc_own = (m ? dtBC_e : dtBC_r) + (size_t)b*KK*LL*14;
  const float* dbc_oth = (m ? dtBC_r : dtBC_e) + (size_t)b*KK*LL*14;
  float* ym = (pg==0) ? (m ? ym_a_e : ym_a_r) : (m ? ym_b_e : ym_b_r);
  ym += (size_t)b*LL*DIN;

  __shared__ float4 db4A[CLEN][4];
  __shared__ float4 db4B[CLEN][4];
  __shared__ float u_s[CLEN*DIN];
  float* dbfA = (float*)db4A;
  float* dbfB = (float*)db4B;

  // stage dt/B (own) + C (other) for both chains
  for(int idx=d; idx<CLEN*14; idx+=DIN){
    int i = idx/14, j = idx%14;
    int slot = (j<6) ? (8+j) : (j-6);
    dbfA[i*16+slot] = dbc_own[((size_t)kA*LL + l0A)*14 + idx];
    dbfB[i*16+slot] = dbc_own[((size_t)kB*LL + l0B)*14 + idx];
  }
  for(int idx=d; idx<CLEN*NS; idx+=DIN){
    int i = idx>>2, j = idx&3;
    dbfA[i*16 + 4 + j] = dbc_oth[((size_t)kA*LL + l0A + i)*14 + 10 + j];
    dbfB[i*16 + 4 + j] = dbc_oth[((size_t)kB*LL + l0B + i)*14 + 10 + j];
  }
  #pragma unroll 8
  for(int i=0;i<CLEN;i++)
    u_s[i*DIN+d] = xc[(size_t)(pos0+i*st)*DIN + d];
  __syncthreads();

  // ---------- loop A: direction kA, forward over segment ----------
  {
    int k = kA;
    float4 al = *(const float4*)&A_logs[(size_t)(k*DIN+d)*NS];
    float A0=-__expf(al.x), A1=-__expf(al.y), A2=-__expf(al.z), A3=-__expf(al.w);
    float Wd[RR];
    #pragma unroll
    for(int r=0;r<RR;r++) Wd[r] = dtw[((size_t)k*DIN + d)*RR + r];
    float bias = dtb[k*DIN+d];
    float Dv = Ds[k*DIN+d];
    int chA = (m*4+b)*4 + kA;  // == m*16+b*4+kA
    size_t hbase = ((size_t)(chA*NCHUNK + cidx)*NS)*DIN + d;
    float h0=hin[hbase], h1=hin[hbase+DIN], h2=hin[hbase+2*DIN], h3=hin[hbase+3*DIN];
    #pragma unroll 4
    for(int i=0;i<CLEN;i++){
      float4 Bv  = db4A[i][0];
      float4 Cv  = db4A[i][1];
      float4 d03 = db4A[i][2];
      float4 d45 = db4A[i][3];
      float dtr = fmaf(d03.x,Wd[0], fmaf(d03.y,Wd[1], fmaf(d03.z,Wd[2],
                  fmaf(d03.w,Wd[3], fmaf(d45.x,Wd[4], fmaf(d45.y,Wd[5], bias))))));
      float dt = fmaxf(dtr,0.f) + __logf(1.f + __expf(-fabsf(dtr)));
      float u = u_s[i*DIN + d];
      float dtu = dt*u;
      h0 = fmaf(h0, __expf(dt*A0), dtu*Bv.x);
      h1 = fmaf(h1, __expf(dt*A1), dtu*Bv.y);
      h2 = fmaf(h2, __expf(dt*A2), dtu*Bv.z);
      h3 = fmaf(h3, __expf(dt*A3), dtu*Bv.w);
      float y = fmaf(h0,Cv.x, fmaf(h1,Cv.y, fmaf(h2,Cv.z, fmaf(h3,Cv.w, Dv*u))));
      ym[(size_t)(pos0+i*st)*DIN + d] = y;
    }
  }
  // ---------- loop B: direction kB, same segment reversed ----------
  {
    int k = kB;
    float4 al = *(const float4*)&A_logs[(size_t)(k*DIN+d)*NS];
    float A0=-__expf(al.x), A1=-__expf(al.y), A2=-__expf(al.z), A3=-__expf(al.w);
    float Wd[RR];
    #pragma unroll
    for(int r=0;r<RR;r++) Wd[r] = dtw[((size_t)k*DIN + d)*RR + r];
    float bias = dtb[k*DIN+d];
    float Dv = Ds[k*DIN+d];
    int chB = (m*4+b)*4 + kB;
    size_t hbase = ((size_t)(chB*NCHUNK + cidx2)*NS)*DIN + d;
    float h0=hin[hbase], h1=hin[hbase+DIN], h2=hin[hbase+2*DIN], h3=hin[hbase+3*DIN];
    #pragma unroll 4
    for(int j=0;j<CLEN;j++){
      int pi = CLEN-1-j;               // position index within segment
      float4 Bv  = db4B[j][0];
      float4 Cv  = db4B[j][1];
      float4 d03 = db4B[j][2];
      float4 d45 = db4B[j][3];
      float dtr = fmaf(d03.x,Wd[0], fmaf(d03.y,Wd[1], fmaf(d03.z,Wd[2],
                  fmaf(d03.w,Wd[3], fmaf(d45.x,Wd[4], fmaf(d45.y,Wd[5], bias))))));
      float dt = fmaxf(dtr,0.f) + __logf(1.f + __expf(-fabsf(dtr)));
      float u = u_s[pi*DIN + d];
      float dtu = dt*u;
      h0 = fmaf(h0, __expf(dt*A0), dtu*Bv.x);
      h1 = fmaf(h1, __expf(dt*A1), dtu*Bv.y);
      h2 = fmaf(h2, __expf(dt*A2), dtu*Bv.z);
      h3 = fmaf(h3, __expf(dt*A3), dtu*Bv.w);
      float y = fmaf(h0,Cv.x, fmaf(h1,Cv.y, fmaf(h2,Cv.z, fmaf(h3,Cv.w, Dv*u))));
      size_t a = (size_t)(pos0+pi*st)*DIN + d;
      ym[a] += y;                      // same thread wrote ym[a] in loop A
    }
  }
}

// ------- K5: LayerNorm(192) over (ym_a+ym_b) + out_proj + residual ---------
// out-proj weights staged through LDS in 16-col tiles (old version read
// w[c*192+dd] scalar per-lane: 64 distinct 768B-apart rows per wave ->
// latency-bound at VALUBusy 31%).
__global__ __launch_bounds__(DIN) void ln_out_kernel(
    const float* __restrict__ ym_a_r, const float* __restrict__ ym_a_e,
    const float* __restrict__ ym_b_r, const float* __restrict__ ym_b_e,
    const float* __restrict__ ln_rg, const float* __restrict__ ln_rb,
    const float* __restrict__ ln_eg, const float* __restrict__ ln_eb,
    const float* __restrict__ opw_r, const float* __restrict__ opw_e,
    const float* __restrict__ x_rgb, const float* __restrict__ x_e,
    float* __restrict__ out){
  int blk = blockIdx.x;                 // m*(NPOS/PB) + g
  int m = blk / (NPOS/PB); int g = blk % (NPOS/PB);
  size_t rem0 = (size_t)g * PB;
  const float* yma = (m ? ym_a_e : ym_a_r) + rem0*DIN;
  const float* ymb = (m ? ym_b_e : ym_b_r) + rem0*DIN;
  int t = threadIdx.x;
  int wid = t>>6;

  float v[PB];
  #pragma unroll
  for(int p=0;p<PB;p++) v[p] = yma[(size_t)p*DIN + t] + ymb[(size_t)p*DIN + t];

  __shared__ float red_s[PB][3], red_q[PB][3];
  #pragma unroll
  for(int p=0;p<PB;p++){
    float s = v[p], q = v[p]*v[p];
    #pragma unroll
    for(int off=32; off>0; off>>=1){ s += __shfl_down(s,off); q += __shfl_down(q,off); }
    if((t&63)==0){ red_s[p][wid]=s; red_q[p][wid]=q; }
  }
  __syncthreads();

  const float* gg = m ? ln_eg : ln_rg;
  const float* be = m ? ln_eb : ln_rb;
  __shared__ float yn_s[PB][DIN];
  float gv = gg[t], bv = be[t];
  #pragma unroll
  for(int p=0;p<PB;p++){
    float S = red_s[p][0]+red_s[p][1]+red_s[p][2];
    float Q = red_q[p][0]+red_q[p][1]+red_q[p][2];
    float mu  = S*(1.f/DIN);
    float var = Q*(1.f/DIN) - mu*mu;
    float inv = rsqrtf(var + 1e-5f);
    yn_s[p][t] = (v[p]-mu)*inv*gv + bv;
  }

  // out-proj: thread t -> c = t%96, pbase = t/96; positions pbase+2*pp
  int c = t % CC;
  int pbase = t / CC;                    // 0 or 1
  const float* w = (m ? opw_e : opw_r);
  __shared__ float wt[CC][17];           // 16-col weight tile, pad 17
  float acc[4] = {0.f,0.f,0.f,0.f};
  for(int d0=0; d0<DIN; d0+=16){
    __syncthreads();                     // also covers yn_s write on 1st iter
    for(int idx=t; idx<CC*16; idx+=DIN){
      int r = idx>>4, cc2 = idx&15;
      wt[r][cc2] = w[(size_t)r*DIN + d0 + cc2];
    }
    __syncthreads();
    #pragma unroll
    for(int cc2=0; cc2<16; cc2++){
      float wv = wt[c][cc2];
      int dd = d0 + cc2;
      #pragma unroll
      for(int pp=0;pp<4;pp++) acc[pp] += yn_s[pbase + 2*pp][dd]*wv;
    }
  }
  const float* xin = m ? x_e : x_rgb;
  #pragma unroll
  for(int pp=0;pp<4;pp++){
    size_t rem = rem0 + pbase + 2*pp;
    size_t oi = (size_t)m*NPOS*CC + rem*CC + c;
    out[oi] = acc[pp] + xin[rem*CC + c];
  }
}

extern "C" void kernel_launch(void* const* d_in, const int* in_sizes, int n_in,
                              void* d_out, int out_size, void* d_ws, size_t ws_size,
                              hipStream_t stream){
  const float* x_rgb = (const float*)d_in[0];
  const float* x_e   = (const float*)d_in[1];
  const float* ipw_r = (const float*)d_in[2];
  const float* ipw_e = (const float*)d_in[3];
  const float* cw_r  = (const float*)d_in[4];
  const float* cb_r  = (const float*)d_in[5];
  const float* cw_e  = (const float*)d_in[6];
  const float* cb_e  = (const float*)d_in[7];
  const float* xpw   = (const float*)d_in[8];
  const float* dtw   = (const float*)d_in[9];
  const float* dtb   = (const float*)d_in[10];
  const float* Alog  = (const float*)d_in[11];
  const float* Ds_   = (const float*)d_in[12];
  const float* ln_rg = (const float*)d_in[13];
  const float* ln_rb = (const float*)d_in[14];
  const float* ln_eg = (const float*)d_in[15];
  const float* ln_eb = (const float*)d_in[16];
  const float* opw_r = (const float*)d_in[17];
  const float* opw_e = (const float*)d_in[18];
  float* out = (float*)d_out;

  float* ws = (float*)d_ws;
  float* xproj_r = ws;
  float* xproj_e = ws + NPD;
  float* xconv_r = ws + 2*NPD;
  float* xconv_e = ws + 3*NPD;
  float* dtBC_r  = ws + 4*NPD;
  float* dtBC_e  = ws + 4*NPD + NDBC;
  float* trans_S = ws + 4*NPD + 2*NDBC;                         // NCHAIN*NCHUNK*NS*DIN
  float* sumdt   = trans_S + (size_t)NCHAIN*NCHUNK*NS*DIN;      // NCHAIN*NCHUNK*DIN
  float* hin     = sumdt   + (size_t)NCHAIN*NCHUNK*DIN;         // NCHAIN*NCHUNK*NS*DIN
  float* ym_b_r  = hin     + (size_t)NCHAIN*NCHUNK*NS*DIN;      // NPD
  float* ym_b_e  = ym_b_r + NPD;                                // NPD
  float* ym_a_r = xproj_r;   // xproj dead after conv
  float* ym_a_e = xproj_e;

  inproj_kernel<<<2*NPOS/PB, DIN, 0, stream>>>(x_rgb, x_e, ipw_r, ipw_e, xproj_r, xproj_e);
  conv_kernel<<<2*NPOS, DIN, 0, stream>>>(xproj_r, xproj_e, cw_r, cb_r, cw_e, cb_e, xconv_r, xconv_e);
  projbc_kernel<<<2*BB*(LL/TPOS), 256, 0, stream>>>(xconv_r, xconv_e, xpw, dtBC_r, dtBC_e);
  scan_p1_kernel<<<NCHAIN*NCHUNK, DIN, 0, stream>>>(xconv_r, xconv_e, dtBC_r, dtBC_e,
                                                    dtw, dtb, Alog, trans_S, sumdt);
  scan_p2_kernel<<<NCHAIN, DIN, 0, stream>>>(trans_S, sumdt, Alog, hin);
  scan_p3_kernel<<<2*BB*2*NCHUNK, DIN, 0, stream>>>(xconv_r, xconv_e, dtBC_r, dtBC_e,
                                                    dtw, dtb, Alog, Ds_, hin,
                                                    ym_a_r, ym_a_e, ym_b_r, ym_b_e);
  ln_out_kernel<<<2*NPOS/PB, DIN, 0, stream>>>(ym_a_r, ym_a_e, ym_b_r, ym_b_e,
                                               ln_rg, ln_rb, ln_eg, ln_eb,
                                               opw_r, opw_e, x_rgb, x_e, out);
}

// Round 12
// 384.632 us; speedup vs baseline: 10.2735x; 1.0696x over previous
//
#include <hip/hip_runtime.h>

#define BB 4
#define HH 64
#define WW 64
#define CC 96
#define DIN 192
#define NS 4
#define RR 6
#define KK 4
#define LL 4096               // HH*WW
#define NPOS (BB*LL)          // 16384 positions per modality
#define NPD ((size_t)NPOS*DIN)
#define NDBC ((size_t)BB*KK*LL*14)
#define NCHUNK 128
#define CLEN 32               // NCHUNK*CLEN == LL ; CLEN must divide 64
#define NCHAIN 32             // 2 mods * 4 b * 4 k
#define PB 8                  // positions per block in inproj
#define TP 16                 // positions per block in ln_out

// canonical spatial position for scan-direction k at scan step l
__device__ __forceinline__ int map_pos(int k, int l){
  switch(k){
    case 0: return l;
    case 1: { int wi=l>>6, hi=l&63; return hi*WW+wi; }     // (w,h) flatten -> h*W+w
    case 2: return LL-1-l;
    default:{ int lr=LL-1-l; int wi=lr>>6, hi=lr&63; return hi*WW+wi; }
  }
}
// within a chunk [l0, l0+CLEN) with CLEN | 64, pos is affine: pos = map_pos(k,l0) + i*stride
__device__ __forceinline__ int pos_stride(int k){
  return (k==0) ? 1 : (k==1) ? WW : (k==2) ? -1 : -WW;
}

// ---------------- K1: in_proj (bhwc,dc->bhwd), 8 positions per block -------
__global__ __launch_bounds__(DIN) void inproj_kernel(
    const float* __restrict__ x_rgb, const float* __restrict__ x_e,
    const float* __restrict__ w_r,   const float* __restrict__ w_e,
    float* __restrict__ xproj_r,    float* __restrict__ xproj_e){
  int blk = blockIdx.x;                 // m*(NPOS/PB) + g
  int m = blk / (NPOS/PB); int g = blk % (NPOS/PB);
  size_t rem0 = (size_t)g * PB;
  const float* x = m ? x_e : x_rgb;
  const float* w = m ? w_e : w_r;
  float* o = m ? xproj_e : xproj_r;
  __shared__ float xs[PB][CC];
  __shared__ float wt[DIN][17];         // 16 cols + pad
  int t = threadIdx.x;
  for(int idx=t; idx<PB*CC; idx+=DIN) xs[idx/CC][idx%CC] = x[rem0*CC + idx];
  float acc[PB];
  #pragma unroll
  for(int p=0;p<PB;p++) acc[p]=0.f;
  for(int c0=0; c0<CC; c0+=16){
    __syncthreads();
    for(int idx=t; idx<DIN*16; idx+=DIN){
      int dd = idx>>4, cc = idx&15;
      wt[dd][cc] = w[(size_t)dd*CC + c0 + cc];
    }
    __syncthreads();
    #pragma unroll
    for(int cc=0; cc<16; cc++){
      float wv = wt[t][cc];
      #pragma unroll
      for(int p=0;p<PB;p++) acc[p] += xs[p][c0+cc]*wv;
    }
  }
  #pragma unroll
  for(int p=0;p<PB;p++) o[(rem0+p)*DIN + t] = acc[p];
}

// ---------------- K2: depthwise 3x3 conv (SAME, zero pad) + bias + SiLU ----
__global__ __launch_bounds__(DIN) void conv_kernel(
    const float* __restrict__ xproj_r, const float* __restrict__ xproj_e,
    const float* __restrict__ cw_r, const float* __restrict__ cb_r,
    const float* __restrict__ cw_e, const float* __restrict__ cb_e,
    float* __restrict__ xconv_r, float* __restrict__ xconv_e){
  int blk = blockIdx.x;
  int m = blk / NPOS; int rem = blk % NPOS;
  int b = rem / LL, p = rem % LL;
  int y = p >> 6, x = p & 63;           // p = y*WW + x
  const float* in = (m ? xproj_e : xproj_r) + (size_t)b*LL*DIN;
  const float* cw = m ? cw_e : cw_r;
  const float* cb = m ? cb_e : cb_r;
  float* out = m ? xconv_e : xconv_r;
  int d = threadIdx.x;
  float acc = cb[d];
  #pragma unroll
  for(int dy=-1;dy<=1;dy++){
    int yy = y+dy; if(yy<0 || yy>=HH) continue;
    #pragma unroll
    for(int dx=-1;dx<=1;dx++){
      int xx = x+dx; if(xx<0 || xx>=WW) continue;
      acc += in[(size_t)(yy*WW+xx)*DIN + d] * cw[d*9 + (dy+1)*3 + (dx+1)];
    }
  }
  float s = acc / (1.f + __expf(-acc));  // silu
  out[(size_t)(b*LL+p)*DIN + d] = s;
}

// -------- K3: x_proj as LDS-tiled mini-GEMM over canonical positions -------
#define TPOS 32               // positions per block
__global__ __launch_bounds__(256) void projbc_kernel(
    const float* __restrict__ xconv_r, const float* __restrict__ xconv_e,
    const float* __restrict__ xpw,
    float* __restrict__ dtBC_r, float* __restrict__ dtBC_e){
  int blk = blockIdx.x;                 // m*(BB*LL/TPOS) + b*(LL/TPOS) + tile
  int m = blk / (BB*LL/TPOS); int rem = blk % (BB*LL/TPOS);
  int b = rem / (LL/TPOS); int p0 = (rem % (LL/TPOS)) * TPOS;
  const float* xc = (m ? xconv_e : xconv_r) + ((size_t)b*LL + p0)*DIN;
  float* o = (m ? dtBC_e : dtBC_r) + (size_t)b*KK*LL*14;

  // stride-97 rows: 97%32==1 -> bank(p*97+d)=(p+d)%32, conflict-free
  __shared__ float xs[TPOS*97];         // 32 pos x 96 d-tile
  __shared__ float wsd[56*97];          // 56 cbar x 96 d-tile

  int t = threadIdx.x;
  int g = t >> 5;                       // 0..7 : handles cbar = g*7 .. g*7+6
  int pl = t & 31;                      // position within tile

  float acc[7];
  #pragma unroll
  for(int j=0;j<7;j++) acc[j]=0.f;

  for(int dt0=0; dt0<DIN; dt0+=96){
    __syncthreads();
    for(int idx=t; idx<TPOS*96; idx+=256){
      int r = idx/96, ccol = idx%96;
      xs[r*97+ccol] = xc[(size_t)r*DIN + dt0 + ccol];
    }
    for(int idx=t; idx<56*96; idx+=256){
      int r = idx/96, ccol = idx%96;
      wsd[r*97+ccol] = xpw[(size_t)r*DIN + dt0 + ccol];
    }
    __syncthreads();
    const float* xrow = &xs[pl*97];
    #pragma unroll 4
    for(int d=0; d<96; d++){
      float xv = xrow[d];
      #pragma unroll
      for(int j=0;j<7;j++) acc[j] += wsd[(g*7+j)*97 + d]*xv;
    }
  }

  int p = p0 + pl;
  int ptr_ = (p&63)*64 + (p>>6);        // inverse of the transpose map
  #pragma unroll
  for(int j=0;j<7;j++){
    int cbar = g*7+j;
    int k = cbar/14, c = cbar%14;
    int l = (k==0) ? p : (k==1) ? ptr_ : (k==2) ? (LL-1-p) : (LL-1-ptr_);
    o[((size_t)k*LL + l)*14 + c] = acc[j];
  }
}

// db4 row layout (16 floats): [0-3]=B, [4-7]=C(p3 only), [8-13]=dtl, [14-15]=pad
// ------- K4a: per-chunk local scan -> (end state S, sum of dt) -------------
__global__ __launch_bounds__(DIN) void scan_p1_kernel(
    const float* __restrict__ xconv_r, const float* __restrict__ xconv_e,
    const float* __restrict__ dtBC_r, const float* __restrict__ dtBC_e,
    const float* __restrict__ dtw, const float* __restrict__ dtb,
    const float* __restrict__ A_logs,
    float* __restrict__ trans_S, float* __restrict__ sumdt){
  int ch = blockIdx.x / NCHUNK;         // m*16 + b*4 + k
  int cidx = blockIdx.x % NCHUNK;
  int m = ch >> 4, b = (ch>>2)&3, k = ch&3;
  int d = threadIdx.x;
  int l0 = cidx*CLEN;

  float4 al = *(const float4*)&A_logs[(size_t)(k*DIN+d)*NS];
  float A0=-__expf(al.x), A1=-__expf(al.y), A2=-__expf(al.z), A3=-__expf(al.w);
  float Wd[RR];
  #pragma unroll
  for(int r=0;r<RR;r++) Wd[r] = dtw[((size_t)k*DIN + d)*RR + r];
  float bias = dtb[k*DIN+d];

  const float* xc    = (m ? xconv_e : xconv_r) + (size_t)b*LL*DIN;
  const float* dbc_m = (m ? dtBC_e : dtBC_r) + ((size_t)b*KK + k)*LL*14;

  __shared__ float4 db4[CLEN][4];
  __shared__ float u_s[CLEN*DIN];
  float* dbf = (float*)db4;

  for(int idx=d; idx<CLEN*14; idx+=DIN){
    int i = idx/14, j = idx%14;
    int slot = (j<6) ? (8+j) : (j-6);
    dbf[i*16+slot] = dbc_m[(size_t)l0*14 + idx];
  }
  int stride = pos_stride(k);
  int pos0 = map_pos(k, l0);
  #pragma unroll 8
  for(int i=0;i<CLEN;i++)
    u_s[i*DIN+d] = xc[(size_t)(pos0+i*stride)*DIN + d];
  __syncthreads();

  float h0=0.f,h1=0.f,h2=0.f,h3=0.f,sd=0.f;
  #pragma unroll 4
  for(int i=0;i<CLEN;i++){
    float4 Bv  = db4[i][0];
    float4 d03 = db4[i][2];
    float4 d45 = db4[i][3];
    float dtr = fmaf(d03.x,Wd[0], fmaf(d03.y,Wd[1], fmaf(d03.z,Wd[2],
                fmaf(d03.w,Wd[3], fmaf(d45.x,Wd[4], fmaf(d45.y,Wd[5], bias))))));
    float dt = fmaxf(dtr,0.f) + __logf(1.f + __expf(-fabsf(dtr)));
    sd += dt;
    float u = u_s[i*DIN + d];
    float dtu = dt*u;
    h0 = fmaf(h0, __expf(dt*A0), dtu*Bv.x);
    h1 = fmaf(h1, __expf(dt*A1), dtu*Bv.y);
    h2 = fmaf(h2, __expf(dt*A2), dtu*Bv.z);
    h3 = fmaf(h3, __expf(dt*A3), dtu*Bv.w);
  }
  size_t base = ((size_t)(ch*NCHUNK + cidx)*NS)*DIN + d;
  trans_S[base          ] = h0;
  trans_S[base +   DIN  ] = h1;
  trans_S[base + 2*DIN  ] = h2;
  trans_S[base + 3*DIN  ] = h3;
  sumdt[(size_t)(ch*NCHUNK + cidx)*DIN + d] = sd;
}

// ------- K4b: sequential inter-chunk scan -> entering state per chunk ------
__global__ __launch_bounds__(DIN) void scan_p2_kernel(
    const float* __restrict__ trans_S, const float* __restrict__ sumdt,
    const float* __restrict__ A_logs, float* __restrict__ hin){
  int ch = blockIdx.x; int k = ch & 3; int d = threadIdx.x;
  float4 al = *(const float4*)&A_logs[(size_t)(k*DIN+d)*NS];
  float A[NS] = {-__expf(al.x), -__expf(al.y), -__expf(al.z), -__expf(al.w)};
  float h[NS] = {0.f,0.f,0.f,0.f};
  for(int c0=0;c0<NCHUNK;c0+=4){
    float S[4][NS], sdv[4];
    #pragma unroll
    for(int cc=0;cc<4;cc++){
      size_t base = ((size_t)(ch*NCHUNK + c0+cc)*NS)*DIN + d;
      #pragma unroll
      for(int n=0;n<NS;n++) S[cc][n] = trans_S[base + (size_t)n*DIN];
      sdv[cc] = sumdt[(size_t)(ch*NCHUNK + c0+cc)*DIN + d];
    }
    #pragma unroll
    for(int cc=0;cc<4;cc++){
      size_t base = ((size_t)(ch*NCHUNK + c0+cc)*NS)*DIN + d;
      #pragma unroll
      for(int n=0;n<NS;n++) hin[base + (size_t)n*DIN] = h[n];
      #pragma unroll
      for(int n=0;n<NS;n++) h[n] = fmaf(h[n], __expf(A[n]*sdv[cc]), S[cc][n]);
    }
  }
}

// ------- K4c: paired-direction chunk scan, atomic-free merge ---------------
// Pair (kA, kB=kA+2) traverse the SAME position segment in opposite order.
// Loop A writes ym[pos] = yA; loop B does ym[pos] += yB (same thread+addr,
// program-order safe). pg=0 pairs k{0,2} -> ym_a; pg=1 pairs k{1,3} -> ym_b.
// ln_out sums ym_a + ym_b. No atomics, no memset.
__global__ __launch_bounds__(DIN) void scan_p3_kernel(
    const float* __restrict__ xconv_r, const float* __restrict__ xconv_e,
    const float* __restrict__ dtBC_r, const float* __restrict__ dtBC_e,
    const float* __restrict__ dtw, const float* __restrict__ dtb,
    const float* __restrict__ A_logs, const float* __restrict__ Ds,
    const float* __restrict__ hin,
    float* __restrict__ ym_a_r, float* __restrict__ ym_a_e,
    float* __restrict__ ym_b_r, float* __restrict__ ym_b_e){
  int blk = blockIdx.x;                 // ((m*4+b)*2+pg)*NCHUNK + cidx
  int cidx = blk % NCHUNK;
  int rem  = blk / NCHUNK;
  int pg = rem & 1; rem >>= 1;
  int b  = rem & 3; int m = rem >> 2;
  int kA = pg, kB = pg + 2;             // paired directions
  int cidx2 = NCHUNK-1-cidx;            // B-chain chunk covering same segment
  int l0A = cidx*CLEN, l0B = cidx2*CLEN;

  int d = threadIdx.x;
  int st = pos_stride(kA);
  int pos0 = map_pos(kA, l0A);

  const float* xc = (m ? xconv_e : xconv_r) + (size_t)b*LL*DIN;
  const float* dbc_own = (m ? dtBC_e : dtBC_r) + (size_t)b*KK*LL*14;
  const float* dbc_oth = (m ? dtBC_r : dtBC_e) + (size_t)b*KK*LL*14;
  float* ym = (pg==0) ? (m ? ym_a_e : ym_a_r) : (m ? ym_b_e : ym_b_r);
  ym += (size_t)b*LL*DIN;

  __shared__ float4 db4A[CLEN][4];
  __shared__ float4 db4B[CLEN][4];
  __shared__ float u_s[CLEN*DIN];
  float* dbfA = (float*)db4A;
  float* dbfB = (float*)db4B;

  // stage dt/B (own) + C (other) for both chains
  for(int idx=d; idx<CLEN*14; idx+=DIN){
    int i = idx/14, j = idx%14;
    int slot = (j<6) ? (8+j) : (j-6);
    dbfA[i*16+slot] = dbc_own[((size_t)kA*LL + l0A)*14 + idx];
    dbfB[i*16+slot] = dbc_own[((size_t)kB*LL + l0B)*14 + idx];
  }
  for(int idx=d; idx<CLEN*NS; idx+=DIN){
    int i = idx>>2, j = idx&3;
    dbfA[i*16 + 4 + j] = dbc_oth[((size_t)kA*LL + l0A + i)*14 + 10 + j];
    dbfB[i*16 + 4 + j] = dbc_oth[((size_t)kB*LL + l0B + i)*14 + 10 + j];
  }
  #pragma unroll 8
  for(int i=0;i<CLEN;i++)
    u_s[i*DIN+d] = xc[(size_t)(pos0+i*st)*DIN + d];
  __syncthreads();

  // ---------- loop A: direction kA, forward over segment ----------
  {
    int k = kA;
    float4 al = *(const float4*)&A_logs[(size_t)(k*DIN+d)*NS];
    float A0=-__expf(al.x), A1=-__expf(al.y), A2=-__expf(al.z), A3=-__expf(al.w);
    float Wd[RR];
    #pragma unroll
    for(int r=0;r<RR;r++) Wd[r] = dtw[((size_t)k*DIN + d)*RR + r];
    float bias = dtb[k*DIN+d];
    float Dv = Ds[k*DIN+d];
    int chA = (m*4+b)*4 + kA;  // == m*16+b*4+kA
    size_t hbase = ((size_t)(chA*NCHUNK + cidx)*NS)*DIN + d;
    float h0=hin[hbase], h1=hin[hbase+DIN], h2=hin[hbase+2*DIN], h3=hin[hbase+3*DIN];
    #pragma unroll 4
    for(int i=0;i<CLEN;i++){
      float4 Bv  = db4A[i][0];
      float4 Cv  = db4A[i][1];
      float4 d03 = db4A[i][2];
      float4 d45 = db4A[i][3];
      float dtr = fmaf(d03.x,Wd[0], fmaf(d03.y,Wd[1], fmaf(d03.z,Wd[2],
                  fmaf(d03.w,Wd[3], fmaf(d45.x,Wd[4], fmaf(d45.y,Wd[5], bias))))));
      float dt = fmaxf(dtr,0.f) + __logf(1.f + __expf(-fabsf(dtr)));
      float u = u_s[i*DIN + d];
      float dtu = dt*u;
      h0 = fmaf(h0, __expf(dt*A0), dtu*Bv.x);
      h1 = fmaf(h1, __expf(dt*A1), dtu*Bv.y);
      h2 = fmaf(h2, __expf(dt*A2), dtu*Bv.z);
      h3 = fmaf(h3, __expf(dt*A3), dtu*Bv.w);
      float y = fmaf(h0,Cv.x, fmaf(h1,Cv.y, fmaf(h2,Cv.z, fmaf(h3,Cv.w, Dv*u))));
      ym[(size_t)(pos0+i*st)*DIN + d] = y;
    }
  }
  // ---------- loop B: direction kB, same segment reversed ----------
  {
    int k = kB;
    float4 al = *(const float4*)&A_logs[(size_t)(k*DIN+d)*NS];
    float A0=-__expf(al.x), A1=-__expf(al.y), A2=-__expf(al.z), A3=-__expf(al.w);
    float Wd[RR];
    #pragma unroll
    for(int r=0;r<RR;r++) Wd[r] = dtw[((size_t)k*DIN + d)*RR + r];
    float bias = dtb[k*DIN+d];
    float Dv = Ds[k*DIN+d];
    int chB = (m*4+b)*4 + kB;
    size_t hbase = ((size_t)(chB*NCHUNK + cidx2)*NS)*DIN + d;
    float h0=hin[hbase], h1=hin[hbase+DIN], h2=hin[hbase+2*DIN], h3=hin[hbase+3*DIN];
    #pragma unroll 4
    for(int j=0;j<CLEN;j++){
      int pi = CLEN-1-j;               // position index within segment
      float4 Bv  = db4B[j][0];
      float4 Cv  = db4B[j][1];
      float4 d03 = db4B[j][2];
      float4 d45 = db4B[j][3];
      float dtr = fmaf(d03.x,Wd[0], fmaf(d03.y,Wd[1], fmaf(d03.z,Wd[2],
                  fmaf(d03.w,Wd[3], fmaf(d45.x,Wd[4], fmaf(d45.y,Wd[5], bias))))));
      float dt = fmaxf(dtr,0.f) + __logf(1.f + __expf(-fabsf(dtr)));
      float u = u_s[pi*DIN + d];
      float dtu = dt*u;
      h0 = fmaf(h0, __expf(dt*A0), dtu*Bv.x);
      h1 = fmaf(h1, __expf(dt*A1), dtu*Bv.y);
      h2 = fmaf(h2, __expf(dt*A2), dtu*Bv.z);
      h3 = fmaf(h3, __expf(dt*A3), dtu*Bv.w);
      float y = fmaf(h0,Cv.x, fmaf(h1,Cv.y, fmaf(h2,Cv.z, fmaf(h3,Cv.w, Dv*u))));
      size_t a = (size_t)(pos0+pi*st)*DIN + d;
      ym[a] += y;                      // same thread wrote ym[a] in loop A
    }
  }
}

// ------- K5: LayerNorm(192) over (ym_a+ym_b) + out_proj + residual ---------
// v3: transposed yn in LDS (yn_t[192][20], f4-aligned rows) + float4 weight
// tiles. GEMM phase: per dd, 2 broadcast b128 yn reads + per-16dd one b128
// weight read -> ~432 LDS instr/thread vs 960 scalar in v2 (LDS-issue-bound).
__global__ __launch_bounds__(256) void ln_out_kernel(
    const float* __restrict__ ym_a_r, const float* __restrict__ ym_a_e,
    const float* __restrict__ ym_b_r, const float* __restrict__ ym_b_e,
    const float* __restrict__ ln_rg, const float* __restrict__ ln_rb,
    const float* __restrict__ ln_eg, const float* __restrict__ ln_eb,
    const float* __restrict__ opw_r, const float* __restrict__ opw_e,
    const float* __restrict__ x_rgb, const float* __restrict__ x_e,
    float* __restrict__ out){
  int blk = blockIdx.x;                 // m*(NPOS/TP) + g
  int m = blk / (NPOS/TP); int g = blk % (NPOS/TP);
  size_t rem0 = (size_t)g * TP;
  int t = threadIdx.x;

  __shared__ float yn_t[DIN][20];       // transposed; row stride 80B (f4-aligned)
  __shared__ float wt[CC][20];          // 16-col weight tile, f4-aligned rows

  // ---- phase 1: LN. 16 groups x 16 lanes; group tp owns position tp ----
  {
    int tp = t >> 4, j = t & 15;        // 12 elems per lane (3 float4)
    const float* yma = (m ? ym_a_e : ym_a_r) + (rem0+tp)*DIN;
    const float* ymb = (m ? ym_b_e : ym_b_r) + (rem0+tp)*DIN;
    float4 v4[3]; float s=0.f, q=0.f;
    #pragma unroll
    for(int e=0;e<3;e++){
      float4 a4 = *(const float4*)&yma[j*12 + e*4];
      float4 b4 = *(const float4*)&ymb[j*12 + e*4];
      v4[e] = make_float4(a4.x+b4.x, a4.y+b4.y, a4.z+b4.z, a4.w+b4.w);
      s += v4[e].x+v4[e].y+v4[e].z+v4[e].w;
      q += v4[e].x*v4[e].x + v4[e].y*v4[e].y + v4[e].z*v4[e].z + v4[e].w*v4[e].w;
    }
    #pragma unroll
    for(int off=8; off>0; off>>=1){ s += __shfl_xor(s,off); q += __shfl_xor(q,off); }
    float mu  = s*(1.f/DIN);
    float var = q*(1.f/DIN) - mu*mu;
    float inv = rsqrtf(var + 1e-5f);
    const float* gg = m ? ln_eg : ln_rg;
    const float* be = m ? ln_eb : ln_rb;
    #pragma unroll
    for(int e=0;e<3;e++){
      int dd = j*12 + e*4;
      float4 g4 = *(const float4*)&gg[dd];
      float4 b4 = *(const float4*)&be[dd];
      yn_t[dd+0][tp] = (v4[e].x-mu)*inv*g4.x + b4.x;
      yn_t[dd+1][tp] = (v4[e].y-mu)*inv*g4.y + b4.y;
      yn_t[dd+2][tp] = (v4[e].z-mu)*inv*g4.z + b4.z;
      yn_t[dd+3][tp] = (v4[e].w-mu)*inv*g4.w + b4.w;
    }
  }

  // ---- phase 2: out-proj GEMM. threads 0..191: c=t%96, pbase=t/96 ----
  int c = t % CC;
  int pbase = t / CC;                   // 0 or 1 (t<192); positions pbase*8..+7
  const float* w = (m ? opw_e : opw_r);
  float acc[8];
  #pragma unroll
  for(int pp=0;pp<8;pp++) acc[pp]=0.f;

  for(int d0=0; d0<DIN; d0+=16){
    __syncthreads();                    // 1st iter: also fences yn_t writes
    for(int idx=t; idx<CC*16; idx+=256){
      int r = idx>>4, cc2 = idx&15;
      wt[r][cc2] = w[(size_t)r*DIN + d0 + cc2];
    }
    __syncthreads();
    if(t < 192){
      #pragma unroll
      for(int q4=0; q4<4; q4++){
        float4 w4 = *(const float4*)&wt[c][q4*4];
        #pragma unroll
        for(int e=0;e<4;e++){
          int dd = d0 + q4*4 + e;
          float wv = (e==0)?w4.x:(e==1)?w4.y:(e==2)?w4.z:w4.w;
          float4 ylo = *(const float4*)&yn_t[dd][pbase*8];
          float4 yhi = *(const float4*)&yn_t[dd][pbase*8+4];
          acc[0] = fmaf(ylo.x, wv, acc[0]);
          acc[1] = fmaf(ylo.y, wv, acc[1]);
          acc[2] = fmaf(ylo.z, wv, acc[2]);
          acc[3] = fmaf(ylo.w, wv, acc[3]);
          acc[4] = fmaf(yhi.x, wv, acc[4]);
          acc[5] = fmaf(yhi.y, wv, acc[5]);
          acc[6] = fmaf(yhi.z, wv, acc[6]);
          acc[7] = fmaf(yhi.w, wv, acc[7]);
        }
      }
    }
  }
  if(t < 192){
    const float* xin = m ? x_e : x_rgb;
    #pragma unroll
    for(int pp=0;pp<8;pp++){
      size_t rem = rem0 + pbase*8 + pp;
      size_t oi = (size_t)m*NPOS*CC + rem*CC + c;
      out[oi] = acc[pp] + xin[rem*CC + c];
    }
  }
}

extern "C" void kernel_launch(void* const* d_in, const int* in_sizes, int n_in,
                              void* d_out, int out_size, void* d_ws, size_t ws_size,
                              hipStream_t stream){
  const float* x_rgb = (const float*)d_in[0];
  const float* x_e   = (const float*)d_in[1];
  const float* ipw_r = (const float*)d_in[2];
  const float* ipw_e = (const float*)d_in[3];
  const float* cw_r  = (const float*)d_in[4];
  const float* cb_r  = (const float*)d_in[5];
  const float* cw_e  = (const float*)d_in[6];
  const float* cb_e  = (const float*)d_in[7];
  const float* xpw   = (const float*)d_in[8];
  const float* dtw   = (const float*)d_in[9];
  const float* dtb   = (const float*)d_in[10];
  const float* Alog  = (const float*)d_in[11];
  const float* Ds_   = (const float*)d_in[12];
  const float* ln_rg = (const float*)d_in[13];
  const float* ln_rb = (const float*)d_in[14];
  const float* ln_eg = (const float*)d_in[15];
  const float* ln_eb = (const float*)d_in[16];
  const float* opw_r = (const float*)d_in[17];
  const float* opw_e = (const float*)d_in[18];
  float* out = (float*)d_out;

  float* ws = (float*)d_ws;
  float* xproj_r = ws;
  float* xproj_e = ws + NPD;
  float* xconv_r = ws + 2*NPD;
  float* xconv_e = ws + 3*NPD;
  float* dtBC_r  = ws + 4*NPD;
  float* dtBC_e  = ws + 4*NPD + NDBC;
  float* trans_S = ws + 4*NPD + 2*NDBC;                         // NCHAIN*NCHUNK*NS*DIN
  float* sumdt   = trans_S + (size_t)NCHAIN*NCHUNK*NS*DIN;      // NCHAIN*NCHUNK*DIN
  float* hin     = sumdt   + (size_t)NCHAIN*NCHUNK*DIN;         // NCHAIN*NCHUNK*NS*DIN
  float* ym_b_r  = hin     + (size_t)NCHAIN*NCHUNK*NS*DIN;      // NPD
  float* ym_b_e  = ym_b_r + NPD;                                // NPD
  float* ym_a_r = xproj_r;   // xproj dead after conv
  float* ym_a_e = xproj_e;

  inproj_kernel<<<2*NPOS/PB, DIN, 0, stream>>>(x_rgb, x_e, ipw_r, ipw_e, xproj_r, xproj_e);
  conv_kernel<<<2*NPOS, DIN, 0, stream>>>(xproj_r, xproj_e, cw_r, cb_r, cw_e, cb_e, xconv_r, xconv_e);
  projbc_kernel<<<2*BB*(LL/TPOS), 256, 0, stream>>>(xconv_r, xconv_e, xpw, dtBC_r, dtBC_e);
  scan_p1_kernel<<<NCHAIN*NCHUNK, DIN, 0, stream>>>(xconv_r, xconv_e, dtBC_r, dtBC_e,
                                                    dtw, dtb, Alog, trans_S, sumdt);
  scan_p2_kernel<<<NCHAIN, DIN, 0, stream>>>(trans_S, sumdt, Alog, hin);
  scan_p3_kernel<<<2*BB*2*NCHUNK, DIN, 0, stream>>>(xconv_r, xconv_e, dtBC_r, dtBC_e,
                                                    dtw, dtb, Alog, Ds_, hin,
                                                    ym_a_r, ym_a_e, ym_b_r, ym_b_e);
  ln_out_kernel<<<2*NPOS/TP, 256, 0, stream>>>(ym_a_r, ym_a_e, ym_b_r, ym_b_e,
                                               ln_rg, ln_rb, ln_eg, ln_eb,
                                               opw_r, opw_e, x_rgb, x_e, out);
}

// Round 13
// 372.961 us; speedup vs baseline: 10.5949x; 1.0313x over previous
//
#include <hip/hip_runtime.h>

#define BB 4
#define HH 64
#define WW 64
#define CC 96
#define DIN 192
#define NS 4
#define RR 6
#define KK 4
#define LL 4096               // HH*WW
#define NPOS (BB*LL)          // 16384 positions per modality
#define NPD ((size_t)NPOS*DIN)
#define NDBC ((size_t)BB*KK*LL*14)
#define NCHUNK 128
#define CLEN 32               // NCHUNK*CLEN == LL ; CLEN must divide 64
#define NCHAIN 32             // 2 mods * 4 b * 4 k
#define PB 16                 // positions per block in inproj
#define TP 16                 // positions per block in ln_out

// canonical spatial position for scan-direction k at scan step l
__device__ __forceinline__ int map_pos(int k, int l){
  switch(k){
    case 0: return l;
    case 1: { int wi=l>>6, hi=l&63; return hi*WW+wi; }     // (w,h) flatten -> h*W+w
    case 2: return LL-1-l;
    default:{ int lr=LL-1-l; int wi=lr>>6, hi=lr&63; return hi*WW+wi; }
  }
}
// within a chunk [l0, l0+CLEN) with CLEN | 64, pos is affine: pos = map_pos(k,l0) + i*stride
__device__ __forceinline__ int pos_stride(int k){
  return (k==0) ? 1 : (k==1) ? WW : (k==2) ? -1 : -WW;
}

// ---------------- K1: in_proj (bhwc,dc->bhwd), 16 positions per block ------
// v2: float4 LDS everywhere. xs4 reads are broadcast (same addr all lanes);
// wt4 rows stride 5 float4 (20 floats) -> start bank 20t+4q covers all 32
// banks exactly 8x/wave = b128 conflict floor. 408 b128 reads + 1536 FMA
// per thread vs 864 scalar reads + 768 FMA in v1 (LDS-issue-bound, 73us).
__global__ __launch_bounds__(DIN) void inproj_kernel(
    const float* __restrict__ x_rgb, const float* __restrict__ x_e,
    const float* __restrict__ w_r,   const float* __restrict__ w_e,
    float* __restrict__ xproj_r,    float* __restrict__ xproj_e){
  int blk = blockIdx.x;                 // m*(NPOS/PB) + g
  int m = blk / (NPOS/PB); int g = blk % (NPOS/PB);
  size_t rem0 = (size_t)g * PB;
  const float* x = m ? x_e : x_rgb;
  const float* w = m ? w_e : w_r;
  float* o = m ? xproj_e : xproj_r;
  __shared__ float4 xs4[PB*24];         // 16 pos x 96 floats
  __shared__ float4 wt4[DIN*5];         // row stride 5 f4; cols c0..c0+15 in [0..3]
  int t = threadIdx.x;

  const float4* xg = (const float4*)(x + rem0*CC);
  xs4[t]       = xg[t];
  xs4[t + 192] = xg[t + 192];

  float acc[PB];
  #pragma unroll
  for(int p=0;p<PB;p++) acc[p]=0.f;

  for(int c0=0; c0<CC; c0+=16){
    __syncthreads();                    // 1st iter also fences xs4
    const float* wr = w + (size_t)t*CC + c0;
    wt4[t*5+0] = *(const float4*)(wr);
    wt4[t*5+1] = *(const float4*)(wr+4);
    wt4[t*5+2] = *(const float4*)(wr+8);
    wt4[t*5+3] = *(const float4*)(wr+12);
    __syncthreads();
    int cq0 = c0 >> 2;
    #pragma unroll
    for(int q=0;q<4;q++){
      float4 w4 = wt4[t*5+q];
      #pragma unroll
      for(int p=0;p<PB;p++){
        float4 x4 = xs4[p*24 + cq0 + q];
        acc[p] = fmaf(x4.x,w4.x, fmaf(x4.y,w4.y, fmaf(x4.z,w4.z, fmaf(x4.w,w4.w, acc[p]))));
      }
    }
  }
  #pragma unroll
  for(int p=0;p<PB;p++) o[(rem0+p)*DIN + t] = acc[p];
}

// ---------------- K2: depthwise 3x3 conv (SAME, zero pad) + bias + SiLU ----
__global__ __launch_bounds__(DIN) void conv_kernel(
    const float* __restrict__ xproj_r, const float* __restrict__ xproj_e,
    const float* __restrict__ cw_r, const float* __restrict__ cb_r,
    const float* __restrict__ cw_e, const float* __restrict__ cb_e,
    float* __restrict__ xconv_r, float* __restrict__ xconv_e){
  int blk = blockIdx.x;
  int m = blk / NPOS; int rem = blk % NPOS;
  int b = rem / LL, p = rem % LL;
  int y = p >> 6, x = p & 63;           // p = y*WW + x
  const float* in = (m ? xproj_e : xproj_r) + (size_t)b*LL*DIN;
  const float* cw = m ? cw_e : cw_r;
  const float* cb = m ? cb_e : cb_r;
  float* out = m ? xconv_e : xconv_r;
  int d = threadIdx.x;
  float acc = cb[d];
  #pragma unroll
  for(int dy=-1;dy<=1;dy++){
    int yy = y+dy; if(yy<0 || yy>=HH) continue;
    #pragma unroll
    for(int dx=-1;dx<=1;dx++){
      int xx = x+dx; if(xx<0 || xx>=WW) continue;
      acc += in[(size_t)(yy*WW+xx)*DIN + d] * cw[d*9 + (dy+1)*3 + (dx+1)];
    }
  }
  float s = acc / (1.f + __expf(-acc));  // silu
  out[(size_t)(b*LL+p)*DIN + d] = s;
}

// -------- K3: x_proj as LDS-tiled mini-GEMM over canonical positions -------
#define TPOS 32               // positions per block
__global__ __launch_bounds__(256) void projbc_kernel(
    const float* __restrict__ xconv_r, const float* __restrict__ xconv_e,
    const float* __restrict__ xpw,
    float* __restrict__ dtBC_r, float* __restrict__ dtBC_e){
  int blk = blockIdx.x;                 // m*(BB*LL/TPOS) + b*(LL/TPOS) + tile
  int m = blk / (BB*LL/TPOS); int rem = blk % (BB*LL/TPOS);
  int b = rem / (LL/TPOS); int p0 = (rem % (LL/TPOS)) * TPOS;
  const float* xc = (m ? xconv_e : xconv_r) + ((size_t)b*LL + p0)*DIN;
  float* o = (m ? dtBC_e : dtBC_r) + (size_t)b*KK*LL*14;

  // stride-97 rows: 97%32==1 -> bank(p*97+d)=(p+d)%32, conflict-free
  __shared__ float xs[TPOS*97];         // 32 pos x 96 d-tile
  __shared__ float wsd[56*97];          // 56 cbar x 96 d-tile

  int t = threadIdx.x;
  int g = t >> 5;                       // 0..7 : handles cbar = g*7 .. g*7+6
  int pl = t & 31;                      // position within tile

  float acc[7];
  #pragma unroll
  for(int j=0;j<7;j++) acc[j]=0.f;

  for(int dt0=0; dt0<DIN; dt0+=96){
    __syncthreads();
    for(int idx=t; idx<TPOS*96; idx+=256){
      int r = idx/96, ccol = idx%96;
      xs[r*97+ccol] = xc[(size_t)r*DIN + dt0 + ccol];
    }
    for(int idx=t; idx<56*96; idx+=256){
      int r = idx/96, ccol = idx%96;
      wsd[r*97+ccol] = xpw[(size_t)r*DIN + dt0 + ccol];
    }
    __syncthreads();
    const float* xrow = &xs[pl*97];
    #pragma unroll 4
    for(int d=0; d<96; d++){
      float xv = xrow[d];
      #pragma unroll
      for(int j=0;j<7;j++) acc[j] += wsd[(g*7+j)*97 + d]*xv;
    }
  }

  int p = p0 + pl;
  int ptr_ = (p&63)*64 + (p>>6);        // inverse of the transpose map
  #pragma unroll
  for(int j=0;j<7;j++){
    int cbar = g*7+j;
    int k = cbar/14, c = cbar%14;
    int l = (k==0) ? p : (k==1) ? ptr_ : (k==2) ? (LL-1-p) : (LL-1-ptr_);
    o[((size_t)k*LL + l)*14 + c] = acc[j];
  }
}

// db4 row layout (16 floats): [0-3]=B, [4-7]=C(p3 only), [8-13]=dtl, [14-15]=pad
// ------- K4a: per-chunk local scan -> (end state S, sum of dt) -------------
__global__ __launch_bounds__(DIN) void scan_p1_kernel(
    const float* __restrict__ xconv_r, const float* __restrict__ xconv_e,
    const float* __restrict__ dtBC_r, const float* __restrict__ dtBC_e,
    const float* __restrict__ dtw, const float* __restrict__ dtb,
    const float* __restrict__ A_logs,
    float* __restrict__ trans_S, float* __restrict__ sumdt){
  int ch = blockIdx.x / NCHUNK;         // m*16 + b*4 + k
  int cidx = blockIdx.x % NCHUNK;
  int m = ch >> 4, b = (ch>>2)&3, k = ch&3;
  int d = threadIdx.x;
  int l0 = cidx*CLEN;

  float4 al = *(const float4*)&A_logs[(size_t)(k*DIN+d)*NS];
  float A0=-__expf(al.x), A1=-__expf(al.y), A2=-__expf(al.z), A3=-__expf(al.w);
  float Wd[RR];
  #pragma unroll
  for(int r=0;r<RR;r++) Wd[r] = dtw[((size_t)k*DIN + d)*RR + r];
  float bias = dtb[k*DIN+d];

  const float* xc    = (m ? xconv_e : xconv_r) + (size_t)b*LL*DIN;
  const float* dbc_m = (m ? dtBC_e : dtBC_r) + ((size_t)b*KK + k)*LL*14;

  __shared__ float4 db4[CLEN][4];
  __shared__ float u_s[CLEN*DIN];
  float* dbf = (float*)db4;

  for(int idx=d; idx<CLEN*14; idx+=DIN){
    int i = idx/14, j = idx%14;
    int slot = (j<6) ? (8+j) : (j-6);
    dbf[i*16+slot] = dbc_m[(size_t)l0*14 + idx];
  }
  int stride = pos_stride(k);
  int pos0 = map_pos(k, l0);
  #pragma unroll 8
  for(int i=0;i<CLEN;i++)
    u_s[i*DIN+d] = xc[(size_t)(pos0+i*stride)*DIN + d];
  __syncthreads();

  float h0=0.f,h1=0.f,h2=0.f,h3=0.f,sd=0.f;
  #pragma unroll 4
  for(int i=0;i<CLEN;i++){
    float4 Bv  = db4[i][0];
    float4 d03 = db4[i][2];
    float4 d45 = db4[i][3];
    float dtr = fmaf(d03.x,Wd[0], fmaf(d03.y,Wd[1], fmaf(d03.z,Wd[2],
                fmaf(d03.w,Wd[3], fmaf(d45.x,Wd[4], fmaf(d45.y,Wd[5], bias))))));
    float dt = fmaxf(dtr,0.f) + __logf(1.f + __expf(-fabsf(dtr)));
    sd += dt;
    float u = u_s[i*DIN + d];
    float dtu = dt*u;
    h0 = fmaf(h0, __expf(dt*A0), dtu*Bv.x);
    h1 = fmaf(h1, __expf(dt*A1), dtu*Bv.y);
    h2 = fmaf(h2, __expf(dt*A2), dtu*Bv.z);
    h3 = fmaf(h3, __expf(dt*A3), dtu*Bv.w);
  }
  size_t base = ((size_t)(ch*NCHUNK + cidx)*NS)*DIN + d;
  trans_S[base          ] = h0;
  trans_S[base +   DIN  ] = h1;
  trans_S[base + 2*DIN  ] = h2;
  trans_S[base + 3*DIN  ] = h3;
  sumdt[(size_t)(ch*NCHUNK + cidx)*DIN + d] = sd;
}

// ------- K4b: sequential inter-chunk scan -> entering state per chunk ------
__global__ __launch_bounds__(DIN) void scan_p2_kernel(
    const float* __restrict__ trans_S, const float* __restrict__ sumdt,
    const float* __restrict__ A_logs, float* __restrict__ hin){
  int ch = blockIdx.x; int k = ch & 3; int d = threadIdx.x;
  float4 al = *(const float4*)&A_logs[(size_t)(k*DIN+d)*NS];
  float A[NS] = {-__expf(al.x), -__expf(al.y), -__expf(al.z), -__expf(al.w)};
  float h[NS] = {0.f,0.f,0.f,0.f};
  for(int c0=0;c0<NCHUNK;c0+=4){
    float S[4][NS], sdv[4];
    #pragma unroll
    for(int cc=0;cc<4;cc++){
      size_t base = ((size_t)(ch*NCHUNK + c0+cc)*NS)*DIN + d;
      #pragma unroll
      for(int n=0;n<NS;n++) S[cc][n] = trans_S[base + (size_t)n*DIN];
      sdv[cc] = sumdt[(size_t)(ch*NCHUNK + c0+cc)*DIN + d];
    }
    #pragma unroll
    for(int cc=0;cc<4;cc++){
      size_t base = ((size_t)(ch*NCHUNK + c0+cc)*NS)*DIN + d;
      #pragma unroll
      for(int n=0;n<NS;n++) hin[base + (size_t)n*DIN] = h[n];
      #pragma unroll
      for(int n=0;n<NS;n++) h[n] = fmaf(h[n], __expf(A[n]*sdv[cc]), S[cc][n]);
    }
  }
}

// ------- K4c: paired-direction chunk scan, atomic-free merge ---------------
// Pair (kA, kB=kA+2) traverse the SAME position segment in opposite order.
// Loop A writes ym[pos] = yA; loop B does ym[pos] += yB (same thread+addr,
// program-order safe). pg=0 pairs k{0,2} -> ym_a; pg=1 pairs k{1,3} -> ym_b.
// ln_out sums ym_a + ym_b. No atomics, no memset.
__global__ __launch_bounds__(DIN) void scan_p3_kernel(
    const float* __restrict__ xconv_r, const float* __restrict__ xconv_e,
    const float* __restrict__ dtBC_r, const float* __restrict__ dtBC_e,
    const float* __restrict__ dtw, const float* __restrict__ dtb,
    const float* __restrict__ A_logs, const float* __restrict__ Ds,
    const float* __restrict__ hin,
    float* __restrict__ ym_a_r, float* __restrict__ ym_a_e,
    float* __restrict__ ym_b_r, float* __restrict__ ym_b_e){
  int blk = blockIdx.x;                 // ((m*4+b)*2+pg)*NCHUNK + cidx
  int cidx = blk % NCHUNK;
  int rem  = blk / NCHUNK;
  int pg = rem & 1; rem >>= 1;
  int b  = rem & 3; int m = rem >> 2;
  int kA = pg, kB = pg + 2;             // paired directions
  int cidx2 = NCHUNK-1-cidx;            // B-chain chunk covering same segment
  int l0A = cidx*CLEN, l0B = cidx2*CLEN;

  int d = threadIdx.x;
  int st = pos_stride(kA);
  int pos0 = map_pos(kA, l0A);

  const float* xc = (m ? xconv_e : xconv_r) + (size_t)b*LL*DIN;
  const float* dbc_own = (m ? dtBC_e : dtBC_r) + (size_t)b*KK*LL*14;
  const float* dbc_oth = (m ? dtBC_r : dtBC_e) + (size_t)b*KK*LL*14;
  float* ym = (pg==0) ? (m ? ym_a_e : ym_a_r) : (m ? ym_b_e : ym_b_r);
  ym += (size_t)b*LL*DIN;

  __shared__ float4 db4A[CLEN][4];
  __shared__ float4 db4B[CLEN][4];
  __shared__ float u_s[CLEN*DIN];
  float* dbfA = (float*)db4A;
  float* dbfB = (float*)db4B;

  // stage dt/B (own) + C (other) for both chains
  for(int idx=d; idx<CLEN*14; idx+=DIN){
    int i = idx/14, j = idx%14;
    int slot = (j<6) ? (8+j) : (j-6);
    dbfA[i*16+slot] = dbc_own[((size_t)kA*LL + l0A)*14 + idx];
    dbfB[i*16+slot] = dbc_own[((size_t)kB*LL + l0B)*14 + idx];
  }
  for(int idx=d; idx<CLEN*NS; idx+=DIN){
    int i = idx>>2, j = idx&3;
    dbfA[i*16 + 4 + j] = dbc_oth[((size_t)kA*LL + l0A + i)*14 + 10 + j];
    dbfB[i*16 + 4 + j] = dbc_oth[((size_t)kB*LL + l0B + i)*14 + 10 + j];
  }
  #pragma unroll 8
  for(int i=0;i<CLEN;i++)
    u_s[i*DIN+d] = xc[(size_t)(pos0+i*st)*DIN + d];
  __syncthreads();

  // ---------- loop A: direction kA, forward over segment ----------
  {
    int k = kA;
    float4 al = *(const float4*)&A_logs[(size_t)(k*DIN+d)*NS];
    float A0=-__expf(al.x), A1=-__expf(al.y), A2=-__expf(al.z), A3=-__expf(al.w);
    float Wd[RR];
    #pragma unroll
    for(int r=0;r<RR;r++) Wd[r] = dtw[((size_t)k*DIN + d)*RR + r];
    float bias = dtb[k*DIN+d];
    float Dv = Ds[k*DIN+d];
    int chA = (m*4+b)*4 + kA;  // == m*16+b*4+kA
    size_t hbase = ((size_t)(chA*NCHUNK + cidx)*NS)*DIN + d;
    float h0=hin[hbase], h1=hin[hbase+DIN], h2=hin[hbase+2*DIN], h3=hin[hbase+3*DIN];
    #pragma unroll 4
    for(int i=0;i<CLEN;i++){
      float4 Bv  = db4A[i][0];
      float4 Cv  = db4A[i][1];
      float4 d03 = db4A[i][2];
      float4 d45 = db4A[i][3];
      float dtr = fmaf(d03.x,Wd[0], fmaf(d03.y,Wd[1], fmaf(d03.z,Wd[2],
                  fmaf(d03.w,Wd[3], fmaf(d45.x,Wd[4], fmaf(d45.y,Wd[5], bias))))));
      float dt = fmaxf(dtr,0.f) + __logf(1.f + __expf(-fabsf(dtr)));
      float u = u_s[i*DIN + d];
      float dtu = dt*u;
      h0 = fmaf(h0, __expf(dt*A0), dtu*Bv.x);
      h1 = fmaf(h1, __expf(dt*A1), dtu*Bv.y);
      h2 = fmaf(h2, __expf(dt*A2), dtu*Bv.z);
      h3 = fmaf(h3, __expf(dt*A3), dtu*Bv.w);
      float y = fmaf(h0,Cv.x, fmaf(h1,Cv.y, fmaf(h2,Cv.z, fmaf(h3,Cv.w, Dv*u))));
      ym[(size_t)(pos0+i*st)*DIN + d] = y;
    }
  }
  // ---------- loop B: direction kB, same segment reversed ----------
  {
    int k = kB;
    float4 al = *(const float4*)&A_logs[(size_t)(k*DIN+d)*NS];
    float A0=-__expf(al.x), A1=-__expf(al.y), A2=-__expf(al.z), A3=-__expf(al.w);
    float Wd[RR];
    #pragma unroll
    for(int r=0;r<RR;r++) Wd[r] = dtw[((size_t)k*DIN + d)*RR + r];
    float bias = dtb[k*DIN+d];
    float Dv = Ds[k*DIN+d];
    int chB = (m*4+b)*4 + kB;
    size_t hbase = ((size_t)(chB*NCHUNK + cidx2)*NS)*DIN + d;
    float h0=hin[hbase], h1=hin[hbase+DIN], h2=hin[hbase+2*DIN], h3=hin[hbase+3*DIN];
    #pragma unroll 4
    for(int j=0;j<CLEN;j++){
      int pi = CLEN-1-j;               // position index within segment
      float4 Bv  = db4B[j][0];
      float4 Cv  = db4B[j][1];
      float4 d03 = db4B[j][2];
      float4 d45 = db4B[j][3];
      float dtr = fmaf(d03.x,Wd[0], fmaf(d03.y,Wd[1], fmaf(d03.z,Wd[2],
                  fmaf(d03.w,Wd[3], fmaf(d45.x,Wd[4], fmaf(d45.y,Wd[5], bias))))));
      float dt = fmaxf(dtr,0.f) + __logf(1.f + __expf(-fabsf(dtr)));
      float u = u_s[pi*DIN + d];
      float dtu = dt*u;
      h0 = fmaf(h0, __expf(dt*A0), dtu*Bv.x);
      h1 = fmaf(h1, __expf(dt*A1), dtu*Bv.y);
      h2 = fmaf(h2, __expf(dt*A2), dtu*Bv.z);
      h3 = fmaf(h3, __expf(dt*A3), dtu*Bv.w);
      float y = fmaf(h0,Cv.x, fmaf(h1,Cv.y, fmaf(h2,Cv.z, fmaf(h3,Cv.w, Dv*u))));
      size_t a = (size_t)(pos0+pi*st)*DIN + d;
      ym[a] += y;                      // same thread wrote ym[a] in loop A
    }
  }
}

// ------- K5: LayerNorm(192) over (ym_a+ym_b) + out_proj + residual ---------
// v3: transposed yn in LDS (yn_t[192][20], f4-aligned rows) + float4 weight
// tiles. GEMM phase: per dd, 2 broadcast b128 yn reads + per-16dd one b128
// weight read -> ~432 LDS instr/thread vs 960 scalar in v2 (LDS-issue-bound).
__global__ __launch_bounds__(256) void ln_out_kernel(
    const float* __restrict__ ym_a_r, const float* __restrict__ ym_a_e,
    const float* __restrict__ ym_b_r, const float* __restrict__ ym_b_e,
    const float* __restrict__ ln_rg, const float* __restrict__ ln_rb,
    const float* __restrict__ ln_eg, const float* __restrict__ ln_eb,
    const float* __restrict__ opw_r, const float* __restrict__ opw_e,
    const float* __restrict__ x_rgb, const float* __restrict__ x_e,
    float* __restrict__ out){
  int blk = blockIdx.x;                 // m*(NPOS/TP) + g
  int m = blk / (NPOS/TP); int g = blk % (NPOS/TP);
  size_t rem0 = (size_t)g * TP;
  int t = threadIdx.x;

  __shared__ float yn_t[DIN][20];       // transposed; row stride 80B (f4-aligned)
  __shared__ float wt[CC][20];          // 16-col weight tile, f4-aligned rows

  // ---- phase 1: LN. 16 groups x 16 lanes; group tp owns position tp ----
  {
    int tp = t >> 4, j = t & 15;        // 12 elems per lane (3 float4)
    const float* yma = (m ? ym_a_e : ym_a_r) + (rem0+tp)*DIN;
    const float* ymb = (m ? ym_b_e : ym_b_r) + (rem0+tp)*DIN;
    float4 v4[3]; float s=0.f, q=0.f;
    #pragma unroll
    for(int e=0;e<3;e++){
      float4 a4 = *(const float4*)&yma[j*12 + e*4];
      float4 b4 = *(const float4*)&ymb[j*12 + e*4];
      v4[e] = make_float4(a4.x+b4.x, a4.y+b4.y, a4.z+b4.z, a4.w+b4.w);
      s += v4[e].x+v4[e].y+v4[e].z+v4[e].w;
      q += v4[e].x*v4[e].x + v4[e].y*v4[e].y + v4[e].z*v4[e].z + v4[e].w*v4[e].w;
    }
    #pragma unroll
    for(int off=8; off>0; off>>=1){ s += __shfl_xor(s,off); q += __shfl_xor(q,off); }
    float mu  = s*(1.f/DIN);
    float var = q*(1.f/DIN) - mu*mu;
    float inv = rsqrtf(var + 1e-5f);
    const float* gg = m ? ln_eg : ln_rg;
    const float* be = m ? ln_eb : ln_rb;
    #pragma unroll
    for(int e=0;e<3;e++){
      int dd = j*12 + e*4;
      float4 g4 = *(const float4*)&gg[dd];
      float4 b4 = *(const float4*)&be[dd];
      yn_t[dd+0][tp] = (v4[e].x-mu)*inv*g4.x + b4.x;
      yn_t[dd+1][tp] = (v4[e].y-mu)*inv*g4.y + b4.y;
      yn_t[dd+2][tp] = (v4[e].z-mu)*inv*g4.z + b4.z;
      yn_t[dd+3][tp] = (v4[e].w-mu)*inv*g4.w + b4.w;
    }
  }

  // ---- phase 2: out-proj GEMM. threads 0..191: c=t%96, pbase=t/96 ----
  int c = t % CC;
  int pbase = t / CC;                   // 0 or 1 (t<192); positions pbase*8..+7
  const float* w = (m ? opw_e : opw_r);
  float acc[8];
  #pragma unroll
  for(int pp=0;pp<8;pp++) acc[pp]=0.f;

  for(int d0=0; d0<DIN; d0+=16){
    __syncthreads();                    // 1st iter: also fences yn_t writes
    for(int idx=t; idx<CC*16; idx+=256){
      int r = idx>>4, cc2 = idx&15;
      wt[r][cc2] = w[(size_t)r*DIN + d0 + cc2];
    }
    __syncthreads();
    if(t < 192){
      #pragma unroll
      for(int q4=0; q4<4; q4++){
        float4 w4 = *(const float4*)&wt[c][q4*4];
        #pragma unroll
        for(int e=0;e<4;e++){
          int dd = d0 + q4*4 + e;
          float wv = (e==0)?w4.x:(e==1)?w4.y:(e==2)?w4.z:w4.w;
          float4 ylo = *(const float4*)&yn_t[dd][pbase*8];
          float4 yhi = *(const float4*)&yn_t[dd][pbase*8+4];
          acc[0] = fmaf(ylo.x, wv, acc[0]);
          acc[1] = fmaf(ylo.y, wv, acc[1]);
          acc[2] = fmaf(ylo.z, wv, acc[2]);
          acc[3] = fmaf(ylo.w, wv, acc[3]);
          acc[4] = fmaf(yhi.x, wv, acc[4]);
          acc[5] = fmaf(yhi.y, wv, acc[5]);
          acc[6] = fmaf(yhi.z, wv, acc[6]);
          acc[7] = fmaf(yhi.w, wv, acc[7]);
        }
      }
    }
  }
  if(t < 192){
    const float* xin = m ? x_e : x_rgb;
    #pragma unroll
    for(int pp=0;pp<8;pp++){
      size_t rem = rem0 + pbase*8 + pp;
      size_t oi = (size_t)m*NPOS*CC + rem*CC + c;
      out[oi] = acc[pp] + xin[rem*CC + c];
    }
  }
}

extern "C" void kernel_launch(void* const* d_in, const int* in_sizes, int n_in,
                              void* d_out, int out_size, void* d_ws, size_t ws_size,
                              hipStream_t stream){
  const float* x_rgb = (const float*)d_in[0];
  const float* x_e   = (const float*)d_in[1];
  const float* ipw_r = (const float*)d_in[2];
  const float* ipw_e = (const float*)d_in[3];
  const float* cw_r  = (const float*)d_in[4];
  const float* cb_r  = (const float*)d_in[5];
  const float* cw_e  = (const float*)d_in[6];
  const float* cb_e  = (const float*)d_in[7];
  const float* xpw   = (const float*)d_in[8];
  const float* dtw   = (const float*)d_in[9];
  const float* dtb   = (const float*)d_in[10];
  const float* Alog  = (const float*)d_in[11];
  const float* Ds_   = (const float*)d_in[12];
  const float* ln_rg = (const float*)d_in[13];
  const float* ln_rb = (const float*)d_in[14];
  const float* ln_eg = (const float*)d_in[15];
  const float* ln_eb = (const float*)d_in[16];
  const float* opw_r = (const float*)d_in[17];
  const float* opw_e = (const float*)d_in[18];
  float* out = (float*)d_out;

  float* ws = (float*)d_ws;
  float* xproj_r = ws;
  float* xproj_e = ws + NPD;
  float* xconv_r = ws + 2*NPD;
  float* xconv_e = ws + 3*NPD;
  float* dtBC_r  = ws + 4*NPD;
  float* dtBC_e  = ws + 4*NPD + NDBC;
  float* trans_S = ws + 4*NPD + 2*NDBC;                         // NCHAIN*NCHUNK*NS*DIN
  float* sumdt   = trans_S + (size_t)NCHAIN*NCHUNK*NS*DIN;      // NCHAIN*NCHUNK*DIN
  float* hin     = sumdt   + (size_t)NCHAIN*NCHUNK*DIN;         // NCHAIN*NCHUNK*NS*DIN
  float* ym_b_r  = hin     + (size_t)NCHAIN*NCHUNK*NS*DIN;      // NPD
  float* ym_b_e  = ym_b_r + NPD;                                // NPD
  float* ym_a_r = xproj_r;   // xproj dead after conv
  float* ym_a_e = xproj_e;

  inproj_kernel<<<2*NPOS/PB, DIN, 0, stream>>>(x_rgb, x_e, ipw_r, ipw_e, xproj_r, xproj_e);
  conv_kernel<<<2*NPOS, DIN, 0, stream>>>(xproj_r, xproj_e, cw_r, cb_r, cw_e, cb_e, xconv_r, xconv_e);
  projbc_kernel<<<2*BB*(LL/TPOS), 256, 0, stream>>>(xconv_r, xconv_e, xpw, dtBC_r, dtBC_e);
  scan_p1_kernel<<<NCHAIN*NCHUNK, DIN, 0, stream>>>(xconv_r, xconv_e, dtBC_r, dtBC_e,
                                                    dtw, dtb, Alog, trans_S, sumdt);
  scan_p2_kernel<<<NCHAIN, DIN, 0, stream>>>(trans_S, sumdt, Alog, hin);
  scan_p3_kernel<<<2*BB*2*NCHUNK, DIN, 0, stream>>>(xconv_r, xconv_e, dtBC_r, dtBC_e,
                                                    dtw, dtb, Alog, Ds_, hin,
                                                    ym_a_r, ym_a_e, ym_b_r, ym_b_e);
  ln_out_kernel<<<2*NPOS/TP, 256, 0, stream>>>(ym_a_r, ym_a_e, ym_b_r, ym_b_e,
                                               ln_rg, ln_rb, ln_eg, ln_eb,
                                               opw_r, opw_e, x_rgb, x_e, out);
}